// Round 2
// baseline (237.095 us; speedup 1.0000x reference)
//
#include <hip/hip_runtime.h>
#include <hip/hip_bf16.h>

// Problem dims (fixed by setup_inputs)
#define BB 8
#define SS 2048
#define DD 1024
#define DKK 128

using bf16x8  = __attribute__((ext_vector_type(8))) __bf16;
using floatx4 = __attribute__((ext_vector_type(4))) float;
using intx4   = __attribute__((ext_vector_type(4))) int;

// async global->LDS, 16B/lane. LDS dest = wave-uniform base + lane*16 (HW rule).
__device__ __forceinline__ void lds16(const void* g, void* l) {
    __builtin_amdgcn_global_load_lds((const __attribute__((address_space(1))) void*)g,
                                     (__attribute__((address_space(3))) void*)l, 16, 0, 0);
}

__device__ __forceinline__ int pack2(float a, float b) {
    union { __bf16 h; unsigned short u; } ua, ub;
    ua.h = (__bf16)a; ub.h = (__bf16)b;
    return (int)(ua.u | ((unsigned)ub.u << 16));
}

// ---------------------------------------------------------------------------
// Kernel 0: W (fp32 [128][1024]) -> bf16, k-tile-major + 16B-block XOR swizzle
// (n,k): tile t=k>>6, 8-elem block kb=(k>>3)&7 stored at kb^(n&7).
// ---------------------------------------------------------------------------
__global__ __launch_bounds__(256) void convw_kernel(
    const float* __restrict__ Wq, const float* __restrict__ Wk,
    const float* __restrict__ Wv, __bf16* __restrict__ Wt)
{
    const int z = blockIdx.y;
    const float* W = (z == 0) ? Wq : (z == 1) ? Wk : Wv;
    const int t  = blockIdx.x * 256 + threadIdx.x;   // 0..16383
    const int n  = t >> 7;
    const int k0 = (t & 127) * 8;
    float4 f0 = *(const float4*)(W + n * DD + k0);
    float4 f1 = *(const float4*)(W + n * DD + k0 + 4);
    bf16x8 v;
    v[0]=(__bf16)f0.x; v[1]=(__bf16)f0.y; v[2]=(__bf16)f0.z; v[3]=(__bf16)f0.w;
    v[4]=(__bf16)f1.x; v[5]=(__bf16)f1.y; v[6]=(__bf16)f1.z; v[7]=(__bf16)f1.w;
    const int kb  = (k0 >> 3) & 7;
    const int kbs = kb ^ (n & 7);
    *(bf16x8*)(Wt + (size_t)z * 131072 + ((k0 >> 6) * 128 + n) * 64 + kbs * 8) = v;
}

// ---------------------------------------------------------------------------
// Kernel 1: projections (unchanged — isolate this round's variables).
// ---------------------------------------------------------------------------
__global__ __launch_bounds__(256, 2) void proj_kernel(
    const float* __restrict__ x, const float* __restrict__ ctx,
    const __bf16* __restrict__ Wt, const int* __restrict__ lengths,
    __bf16* __restrict__ Qb, __bf16* __restrict__ Kb, __bf16* __restrict__ Vt)
{
    __shared__ __align__(16) __bf16 SH[20992];      // 41984 B
    __bf16* Abuf = SH;                              // 64 x 72 (padded)
    __bf16* Wl0  = SH + 4608;                       // 128 x 64 (swizzled image)
    __bf16* Wl1  = SH + 12800;
    __bf16* T    = SH + 4608;                       // V epilogue overlay, 128 x 72

    const int isV = blockIdx.x >= 256;
    const int m0  = (isV ? blockIdx.x - 256 : blockIdx.x) * 64;
    const int b   = m0 >> 11;
    const int s0  = m0 & (SS - 1);
    const int len = lengths[b];
    if (s0 >= len) return;                          // fully-padded tile

    const int tid  = threadIdx.x;
    const int wave = tid >> 6;
    const int lane = tid & 63;
    const int quad = lane >> 4;
    const int l16  = lane & 15;
    const int wm   = wave >> 1;
    const int wn   = wave & 1;

    const float*  A  = isV ? x : ctx;
    const __bf16* W0 = isV ? (Wt + 262144) : Wt;
    const __bf16* W1 = Wt + 131072;

    const int r    = tid >> 2;
    const int kseg = (tid & 3) * 16;
    const float* Ab = A + (size_t)(m0 + r) * DD + kseg;

    floatx4 acc[2][2][4];
#pragma unroll
    for (int m_ = 0; m_ < 2; ++m_)
#pragma unroll
        for (int i = 0; i < 2; ++i)
#pragma unroll
            for (int j = 0; j < 4; ++j) acc[m_][i][j] = (floatx4){0.f,0.f,0.f,0.f};

    float4 pf[4];
#pragma unroll
    for (int i = 0; i < 4; ++i) pf[i] = *(const float4*)(Ab + i * 4);

    for (int t = 0; t < 16; ++t) {
        __syncthreads();
        {
            bf16x8 c0, c1;
            c0[0]=(__bf16)pf[0].x; c0[1]=(__bf16)pf[0].y; c0[2]=(__bf16)pf[0].z; c0[3]=(__bf16)pf[0].w;
            c0[4]=(__bf16)pf[1].x; c0[5]=(__bf16)pf[1].y; c0[6]=(__bf16)pf[1].z; c0[7]=(__bf16)pf[1].w;
            c1[0]=(__bf16)pf[2].x; c1[1]=(__bf16)pf[2].y; c1[2]=(__bf16)pf[2].z; c1[3]=(__bf16)pf[2].w;
            c1[4]=(__bf16)pf[3].x; c1[5]=(__bf16)pf[3].y; c1[6]=(__bf16)pf[3].z; c1[7]=(__bf16)pf[3].w;
            *(bf16x8*)&Abuf[r * 72 + kseg]     = c0;
            *(bf16x8*)&Abuf[r * 72 + kseg + 8] = c1;
        }
#pragma unroll
        for (int i = 0; i < 4; ++i) {
            const int c = wave * 4 + i;
            lds16(W0 + (size_t)t * 8192 + c * 512 + lane * 8, Wl0 + c * 512);
            if (!isV)
                lds16(W1 + (size_t)t * 8192 + c * 512 + lane * 8, Wl1 + c * 512);
        }
        if (t < 15) {
            const float* ap = Ab + (t + 1) * 64;
#pragma unroll
            for (int i = 0; i < 4; ++i) pf[i] = *(const float4*)(ap + i * 4);
        }
        __syncthreads();

#pragma unroll
        for (int kh = 0; kh < 2; ++kh) {
            bf16x8 af[2];
#pragma unroll
            for (int mt = 0; mt < 2; ++mt)
                af[mt] = *(const bf16x8*)&Abuf[(wm*32 + mt*16 + l16) * 72 + kh*32 + quad*8];
            const int kb = kh * 4 + quad;
#pragma unroll
            for (int nt = 0; nt < 4; ++nt) {
                const int n = wn * 64 + nt * 16 + l16;
                const int off = n * 64 + ((kb ^ (n & 7)) << 3);
                bf16x8 w0 = *(const bf16x8*)&Wl0[off];
#pragma unroll
                for (int mt = 0; mt < 2; ++mt)
                    acc[0][mt][nt] = __builtin_amdgcn_mfma_f32_16x16x32_bf16(af[mt], w0, acc[0][mt][nt], 0, 0, 0);
                if (!isV) {
                    bf16x8 w1 = *(const bf16x8*)&Wl1[off];
#pragma unroll
                    for (int mt = 0; mt < 2; ++mt)
                        acc[1][mt][nt] = __builtin_amdgcn_mfma_f32_16x16x32_bf16(af[mt], w1, acc[1][mt][nt], 0, 0, 0);
                }
            }
        }
    }

    if (!isV) {
#pragma unroll
        for (int mt = 0; mt < 2; ++mt)
#pragma unroll
            for (int rr = 0; rr < 4; ++rr) {
                const int row = m0 + wm*32 + mt*16 + quad*4 + rr;
                const float mk = ((row & (SS - 1)) < len) ? 1.f : 0.f;
#pragma unroll
                for (int nt = 0; nt < 4; ++nt) {
                    const int col = wn*64 + nt*16 + l16;
                    Qb[(size_t)row * DKK + col] = (__bf16)(acc[0][mt][nt][rr] * mk);
                    Kb[(size_t)row * DKK + col] = (__bf16)(acc[1][mt][nt][rr] * mk);
                }
            }
    } else {
        __syncthreads();
#pragma unroll
        for (int mt = 0; mt < 2; ++mt)
#pragma unroll
            for (int nt = 0; nt < 4; ++nt)
#pragma unroll
                for (int rr = 0; rr < 4; ++rr) {
                    const int s = wm*32 + mt*16 + quad*4 + rr;
                    const int n = wn*64 + nt*16 + l16;
                    const float mk = (s0 + s < len) ? 1.f : 0.f;
                    T[n * 72 + s] = (__bf16)(acc[0][mt][nt][rr] * mk);
                }
        __syncthreads();
        const int n = tid >> 1, h = tid & 1;
        __bf16* dst = Vt + (size_t)b * DKK * SS + (size_t)n * SS + s0 + h * 32;
#pragma unroll
        for (int i = 0; i < 4; ++i)
            *(bf16x8*)(dst + i * 8) = *(const bf16x8*)&T[n * 72 + h * 32 + i * 8];
    }
}

// ---------------------------------------------------------------------------
// Kernel 2: per-batch column mean of V (exact output for padded q-rows).
// ---------------------------------------------------------------------------
__global__ __launch_bounds__(256) void vmean_kernel(
    const __bf16* __restrict__ Vt, const int* __restrict__ lengths,
    float* __restrict__ Vmean)
{
    const int b   = blockIdx.x >> 3;
    const int g3  = blockIdx.x & 7;
    const int len = lengths[b];
    const int tid = threadIdx.x;
    const int n   = g3 * 16 + (tid >> 4);
    const int sl  = (tid & 15) * 128;                 // this thread's 128-elem span
    const __bf16* src = Vt + (size_t)b * DKK * SS + (size_t)n * SS + sl;
    float s = 0.f;
#pragma unroll
    for (int i = 0; i < 16; ++i) {
        bf16x8 v = *(const bf16x8*)(src + i * 8);
#pragma unroll
        for (int j = 0; j < 8; ++j)
            s += (sl + i * 8 + j < len) ? (float)v[j] : 0.f;
    }
#pragma unroll
    for (int off = 1; off < 16; off <<= 1)
        s += __shfl_xor(s, off, 64);
    if ((tid & 15) == 0) Vmean[b * DKK + n] = s / (float)len;
}

// ---------------------------------------------------------------------------
// Kernel 3: flash attention, one wave owns one 16-row q-tile, ALL its keys.
// No atomics, no partial buffers: fixed-max softmax accumulates oacc/lsum in
// registers; final out = oacc * (1/lsum) written once (fp32).
//   - b = blockIdx&7 pins each batch to one XCD (K/V = 1 MB -> L2-resident).
//   - K fragments double-buffered (prefetch next 32 keys before MFMA block);
//     V issued at top of process so its latency hides under QK+softmax.
//   - 1024 single-wave blocks, ~190 VGPR -> all co-resident; causal imbalance
//     absorbed by co-residency (longest tile = 64 iters).
// ---------------------------------------------------------------------------
__global__ __launch_bounds__(64) void attn_kernel(
    const __bf16* __restrict__ Qb, const __bf16* __restrict__ Kb,
    const __bf16* __restrict__ Vt, const int* __restrict__ lengths,
    const float* __restrict__ Vmean, float* __restrict__ out)
{
    const int b    = blockIdx.x & 7;          // batch -> XCD pin (round-robin)
    const int t    = 127 - (blockIdx.x >> 3); // longest tiles dispatch first
    const int qw   = t * 16;
    const int len  = lengths[b];
    const int lane = threadIdx.x;
    const int quad = lane >> 4;
    const int l16  = lane & 15;

    if (qw >= len) {                          // fully-padded tile: exact Vmean
        const float4 v0 = *(const float4*)(Vmean + b * DKK + l16 * 8);
        const float4 v1 = *(const float4*)(Vmean + b * DKK + l16 * 8 + 4);
#pragma unroll
        for (int rr = 0; rr < 4; ++rr) {
            float* p = out + (size_t)(b * SS + qw + quad * 4 + rr) * DKK + l16 * 8;
            *(float4*)p = v0; *(float4*)(p + 4) = v1;
        }
        return;
    }

    const int jmax = min(qw + 16, len);       // causal: keys in [0, jmax)
    const __bf16* Qbase = Qb + (size_t)(b * SS + qw) * DKK;
    const __bf16* Kbase = Kb + (size_t)b * SS * DKK;
    const __bf16* Vbase = Vt + (size_t)b * DKK * SS;

    bf16x8 qfrag[4];
#pragma unroll
    for (int cc = 0; cc < 4; ++cc)
        qfrag[cc] = *(const bf16x8*)(Qbase + (size_t)l16 * DKK + cc * 32 + quad * 8);

    floatx4 oacc[8];
#pragma unroll
    for (int nt = 0; nt < 8; ++nt) oacc[nt] = (floatx4){0.f,0.f,0.f,0.f};
    float lsum = 0.f;                         // per-lane, q = l16
    const float scale = 0.08838834764831845f; // 1/sqrt(128)
    const int   iq    = qw + l16;

    auto loadK = [&](bf16x8 (&kf)[2][4], int j0) {
#pragma unroll
        for (int jt = 0; jt < 2; ++jt)
#pragma unroll
            for (int cc = 0; cc < 4; ++cc)
                kf[jt][cc] = *(const bf16x8*)(
                    Kbase + (size_t)(j0 + jt*16 + l16) * DKK + cc*32 + quad*8);
    };
    auto process = [&](const bf16x8 (&kf)[2][4], int j0) {
        bf16x8 vf[8];                          // issue V first: latency hides
#pragma unroll                                 // under QK MFMA + softmax chain
        for (int nt = 0; nt < 8; ++nt)
            vf[nt] = *(const bf16x8*)(Vbase + (size_t)(nt*16 + l16) * SS + j0 + quad*8);

        // S^T[key][q]: A = K-frag (m=key), B = Q-frag (n=q)   (verified R5)
        floatx4 st[2];
#pragma unroll
        for (int jt = 0; jt < 2; ++jt) {
            st[jt] = (floatx4){0.f,0.f,0.f,0.f};
#pragma unroll
            for (int cc = 0; cc < 4; ++cc)
                st[jt] = __builtin_amdgcn_mfma_f32_16x16x32_bf16(
                    kf[jt][cc], qfrag[cc], st[jt], 0, 0, 0);
        }
        int pk[2][2];
#pragma unroll
        for (int jt = 0; jt < 2; ++jt) {
            float p[4];
#pragma unroll
            for (int rr = 0; rr < 4; ++rr) {
                const int j = j0 + jt*16 + quad*4 + rr;
                // j>=len needed: tail loads past len are zeroed K rows -> p
                // would be exp(-8) and inflate lsum for padded q-rows.
                p[rr] = (j > iq || j >= len) ? 0.f : __expf(st[jt][rr] * scale - 8.f);
                lsum += p[rr];
            }
            pk[jt][0] = pack2(p[0], p[1]);
            pk[jt][1] = pack2(p[2], p[3]);
        }
        // C->A layout via cross-lane pull (verified R5)
        const int a0 = (((quad & 1) << 5) + l16) << 2;
        const int a1 = a0 + 64;
        const int r00 = __builtin_amdgcn_ds_bpermute(a0, pk[0][0]);
        const int r01 = __builtin_amdgcn_ds_bpermute(a0, pk[0][1]);
        const int r02 = __builtin_amdgcn_ds_bpermute(a0, pk[1][0]);
        const int r03 = __builtin_amdgcn_ds_bpermute(a0, pk[1][1]);
        const int r10 = __builtin_amdgcn_ds_bpermute(a1, pk[0][0]);
        const int r11 = __builtin_amdgcn_ds_bpermute(a1, pk[0][1]);
        const int r12 = __builtin_amdgcn_ds_bpermute(a1, pk[1][0]);
        const int r13 = __builtin_amdgcn_ds_bpermute(a1, pk[1][1]);
        const bool hi = quad >= 2;
        union { intx4 i; bf16x8 h; } u;
        u.i = (intx4){ hi ? r02 : r00, hi ? r03 : r01,
                       hi ? r12 : r10, hi ? r13 : r11 };
#pragma unroll
        for (int nt = 0; nt < 8; ++nt)
            oacc[nt] = __builtin_amdgcn_mfma_f32_16x16x32_bf16(u.h, vf[nt], oacc[nt], 0, 0, 0);
    };

    bf16x8 kfA[2][4], kfB[2][4];
    loadK(kfA, 0);
    int j0 = 0;
    while (true) {
        bool more = (j0 + 32 < jmax);
        if (more) loadK(kfB, j0 + 32);        // prefetch next K tile
        process(kfA, j0);
        j0 += 32;
        if (!more) break;
        more = (j0 + 32 < jmax);
        if (more) loadK(kfA, j0 + 32);
        process(kfB, j0);
        j0 += 32;
        if (!more) break;
    }

    // reduce lsum over the 4 quads -> every lane holds row-total for q = l16
    lsum += __shfl_xor(lsum, 16, 64);
    lsum += __shfl_xor(lsum, 32, 64);
    // O: C/D layout row(q) = quad*4+rr, col(dk) = nt*16+l16; fetch that row's
    // denominator from lane (quad*4+rr) and write final output directly.
    float inv[4];
#pragma unroll
    for (int rr = 0; rr < 4; ++rr)
        inv[rr] = 1.f / __shfl(lsum, quad * 4 + rr, 64);
#pragma unroll
    for (int nt = 0; nt < 8; ++nt)
#pragma unroll
        for (int rr = 0; rr < 4; ++rr)
            out[(size_t)(b * SS + qw + quad*4 + rr) * DKK + nt*16 + l16] =
                oacc[nt][rr] * inv[rr];
}

extern "C" void kernel_launch(void* const* d_in, const int* in_sizes, int n_in,
                              void* d_out, int out_size, void* d_ws, size_t ws_size,
                              hipStream_t stream) {
    const float* x   = (const float*)d_in[0];
    const float* ctx = (const float*)d_in[1];
    const float* Wq  = (const float*)d_in[2];
    const float* Wk  = (const float*)d_in[3];
    const float* Wv  = (const float*)d_in[4];
    const int* lengths = (const int*)d_in[5];
    float* out = (float*)d_out;

    char* ws = (char*)d_ws;
    __bf16* Wt = (__bf16*)ws;                          // 768 KB
    __bf16* Qb = (__bf16*)(ws + 786432);               // 4 MB
    __bf16* Kb = (__bf16*)(ws + 786432 + 4194304);     // 4 MB
    __bf16* Vt = (__bf16*)(ws + 786432 + 8388608);     // 4 MB (V^T)
    float*  Vm = (float*) (ws + 786432 + 12582912);    // 4 KB
    // total ~12.8 MB (no Oacc/Lacc/memset needed anymore)

    convw_kernel<<<dim3(64, 3), 256, 0, stream>>>(Wq, Wk, Wv, Wt);
    proj_kernel<<<512, 256, 0, stream>>>(x, ctx, Wt, lengths, Qb, Kb, Vt);
    vmean_kernel<<<64, 256, 0, stream>>>(Vt, lengths, Vm);
    attn_kernel<<<1024, 64, 0, stream>>>(Qb, Kb, Vt, lengths, Vm, out);
}

// Round 3
// 234.567 us; speedup vs baseline: 1.0108x; 1.0108x over previous
//
#include <hip/hip_runtime.h>
#include <hip/hip_bf16.h>

// Problem dims (fixed by setup_inputs)
#define BB 8
#define SS 2048
#define DD 1024
#define DKK 128

using bf16x8  = __attribute__((ext_vector_type(8))) __bf16;
using floatx4 = __attribute__((ext_vector_type(4))) float;
using intx4   = __attribute__((ext_vector_type(4))) int;

// async global->LDS, 16B/lane. LDS dest = wave-uniform base + lane*16 (HW rule).
__device__ __forceinline__ void lds16(const void* g, void* l) {
    __builtin_amdgcn_global_load_lds((const __attribute__((address_space(1))) void*)g,
                                     (__attribute__((address_space(3))) void*)l, 16, 0, 0);
}

__device__ __forceinline__ int pack2(float a, float b) {
    union { __bf16 h; unsigned short u; } ua, ub;
    ua.h = (__bf16)a; ub.h = (__bf16)b;
    return (int)(ua.u | ((unsigned)ub.u << 16));
}

// ---------------------------------------------------------------------------
// Kernel 0: W (fp32 [128][1024]) -> bf16, k-tile-major + 16B-block XOR swizzle
// (n,k): tile t=k>>6, 8-elem block kb=(k>>3)&7 stored at kb^(n&7).
// ---------------------------------------------------------------------------
__global__ __launch_bounds__(256) void convw_kernel(
    const float* __restrict__ Wq, const float* __restrict__ Wk,
    const float* __restrict__ Wv, __bf16* __restrict__ Wt)
{
    const int z = blockIdx.y;
    const float* W = (z == 0) ? Wq : (z == 1) ? Wk : Wv;
    const int t  = blockIdx.x * 256 + threadIdx.x;   // 0..16383
    const int n  = t >> 7;
    const int k0 = (t & 127) * 8;
    float4 f0 = *(const float4*)(W + n * DD + k0);
    float4 f1 = *(const float4*)(W + n * DD + k0 + 4);
    bf16x8 v;
    v[0]=(__bf16)f0.x; v[1]=(__bf16)f0.y; v[2]=(__bf16)f0.z; v[3]=(__bf16)f0.w;
    v[4]=(__bf16)f1.x; v[5]=(__bf16)f1.y; v[6]=(__bf16)f1.z; v[7]=(__bf16)f1.w;
    const int kb  = (k0 >> 3) & 7;
    const int kbs = kb ^ (n & 7);
    *(bf16x8*)(Wt + (size_t)z * 131072 + ((k0 >> 6) * 128 + n) * 64 + kbs * 8) = v;
}

// ---------------------------------------------------------------------------
// Kernel 1: projections (unchanged — isolate this round's variables).
// ---------------------------------------------------------------------------
__global__ __launch_bounds__(256, 2) void proj_kernel(
    const float* __restrict__ x, const float* __restrict__ ctx,
    const __bf16* __restrict__ Wt, const int* __restrict__ lengths,
    __bf16* __restrict__ Qb, __bf16* __restrict__ Kb, __bf16* __restrict__ Vt)
{
    __shared__ __align__(16) __bf16 SH[20992];      // 41984 B
    __bf16* Abuf = SH;                              // 64 x 72 (padded)
    __bf16* Wl0  = SH + 4608;                       // 128 x 64 (swizzled image)
    __bf16* Wl1  = SH + 12800;
    __bf16* T    = SH + 4608;                       // V epilogue overlay, 128 x 72

    const int isV = blockIdx.x >= 256;
    const int m0  = (isV ? blockIdx.x - 256 : blockIdx.x) * 64;
    const int b   = m0 >> 11;
    const int s0  = m0 & (SS - 1);
    const int len = lengths[b];
    if (s0 >= len) return;                          // fully-padded tile

    const int tid  = threadIdx.x;
    const int wave = tid >> 6;
    const int lane = tid & 63;
    const int quad = lane >> 4;
    const int l16  = lane & 15;
    const int wm   = wave >> 1;
    const int wn   = wave & 1;

    const float*  A  = isV ? x : ctx;
    const __bf16* W0 = isV ? (Wt + 262144) : Wt;
    const __bf16* W1 = Wt + 131072;

    const int r    = tid >> 2;
    const int kseg = (tid & 3) * 16;
    const float* Ab = A + (size_t)(m0 + r) * DD + kseg;

    floatx4 acc[2][2][4];
#pragma unroll
    for (int m_ = 0; m_ < 2; ++m_)
#pragma unroll
        for (int i = 0; i < 2; ++i)
#pragma unroll
            for (int j = 0; j < 4; ++j) acc[m_][i][j] = (floatx4){0.f,0.f,0.f,0.f};

    float4 pf[4];
#pragma unroll
    for (int i = 0; i < 4; ++i) pf[i] = *(const float4*)(Ab + i * 4);

    for (int t = 0; t < 16; ++t) {
        __syncthreads();
        {
            bf16x8 c0, c1;
            c0[0]=(__bf16)pf[0].x; c0[1]=(__bf16)pf[0].y; c0[2]=(__bf16)pf[0].z; c0[3]=(__bf16)pf[0].w;
            c0[4]=(__bf16)pf[1].x; c0[5]=(__bf16)pf[1].y; c0[6]=(__bf16)pf[1].z; c0[7]=(__bf16)pf[1].w;
            c1[0]=(__bf16)pf[2].x; c1[1]=(__bf16)pf[2].y; c1[2]=(__bf16)pf[2].z; c1[3]=(__bf16)pf[2].w;
            c1[4]=(__bf16)pf[3].x; c1[5]=(__bf16)pf[3].y; c1[6]=(__bf16)pf[3].z; c1[7]=(__bf16)pf[3].w;
            *(bf16x8*)&Abuf[r * 72 + kseg]     = c0;
            *(bf16x8*)&Abuf[r * 72 + kseg + 8] = c1;
        }
#pragma unroll
        for (int i = 0; i < 4; ++i) {
            const int c = wave * 4 + i;
            lds16(W0 + (size_t)t * 8192 + c * 512 + lane * 8, Wl0 + c * 512);
            if (!isV)
                lds16(W1 + (size_t)t * 8192 + c * 512 + lane * 8, Wl1 + c * 512);
        }
        if (t < 15) {
            const float* ap = Ab + (t + 1) * 64;
#pragma unroll
            for (int i = 0; i < 4; ++i) pf[i] = *(const float4*)(ap + i * 4);
        }
        __syncthreads();

#pragma unroll
        for (int kh = 0; kh < 2; ++kh) {
            bf16x8 af[2];
#pragma unroll
            for (int mt = 0; mt < 2; ++mt)
                af[mt] = *(const bf16x8*)&Abuf[(wm*32 + mt*16 + l16) * 72 + kh*32 + quad*8];
            const int kb = kh * 4 + quad;
#pragma unroll
            for (int nt = 0; nt < 4; ++nt) {
                const int n = wn * 64 + nt * 16 + l16;
                const int off = n * 64 + ((kb ^ (n & 7)) << 3);
                bf16x8 w0 = *(const bf16x8*)&Wl0[off];
#pragma unroll
                for (int mt = 0; mt < 2; ++mt)
                    acc[0][mt][nt] = __builtin_amdgcn_mfma_f32_16x16x32_bf16(af[mt], w0, acc[0][mt][nt], 0, 0, 0);
                if (!isV) {
                    bf16x8 w1 = *(const bf16x8*)&Wl1[off];
#pragma unroll
                    for (int mt = 0; mt < 2; ++mt)
                        acc[1][mt][nt] = __builtin_amdgcn_mfma_f32_16x16x32_bf16(af[mt], w1, acc[1][mt][nt], 0, 0, 0);
                }
            }
        }
    }

    if (!isV) {
#pragma unroll
        for (int mt = 0; mt < 2; ++mt)
#pragma unroll
            for (int rr = 0; rr < 4; ++rr) {
                const int row = m0 + wm*32 + mt*16 + quad*4 + rr;
                const float mk = ((row & (SS - 1)) < len) ? 1.f : 0.f;
#pragma unroll
                for (int nt = 0; nt < 4; ++nt) {
                    const int col = wn*64 + nt*16 + l16;
                    Qb[(size_t)row * DKK + col] = (__bf16)(acc[0][mt][nt][rr] * mk);
                    Kb[(size_t)row * DKK + col] = (__bf16)(acc[1][mt][nt][rr] * mk);
                }
            }
    } else {
        __syncthreads();
#pragma unroll
        for (int mt = 0; mt < 2; ++mt)
#pragma unroll
            for (int nt = 0; nt < 4; ++nt)
#pragma unroll
                for (int rr = 0; rr < 4; ++rr) {
                    const int s = wm*32 + mt*16 + quad*4 + rr;
                    const int n = wn*64 + nt*16 + l16;
                    const float mk = (s0 + s < len) ? 1.f : 0.f;
                    T[n * 72 + s] = (__bf16)(acc[0][mt][nt][rr] * mk);
                }
        __syncthreads();
        const int n = tid >> 1, h = tid & 1;
        __bf16* dst = Vt + (size_t)b * DKK * SS + (size_t)n * SS + s0 + h * 32;
#pragma unroll
        for (int i = 0; i < 4; ++i)
            *(bf16x8*)(dst + i * 8) = *(const bf16x8*)&T[n * 72 + h * 32 + i * 8];
    }
}

// ---------------------------------------------------------------------------
// Kernel 2: per-batch column mean of V (exact output for padded q-rows).
// ---------------------------------------------------------------------------
__global__ __launch_bounds__(256) void vmean_kernel(
    const __bf16* __restrict__ Vt, const int* __restrict__ lengths,
    float* __restrict__ Vmean)
{
    const int b   = blockIdx.x >> 3;
    const int g3  = blockIdx.x & 7;
    const int len = lengths[b];
    const int tid = threadIdx.x;
    const int n   = g3 * 16 + (tid >> 4);
    const int sl  = (tid & 15) * 128;                 // this thread's 128-elem span
    const __bf16* src = Vt + (size_t)b * DKK * SS + (size_t)n * SS + sl;
    float s = 0.f;
#pragma unroll
    for (int i = 0; i < 16; ++i) {
        bf16x8 v = *(const bf16x8*)(src + i * 8);
#pragma unroll
        for (int j = 0; j < 8; ++j)
            s += (sl + i * 8 + j < len) ? (float)v[j] : 0.f;
    }
#pragma unroll
    for (int off = 1; off < 16; off <<= 1)
        s += __shfl_xor(s, off, 64);
    if ((tid & 15) == 0) Vmean[b * DKK + n] = s / (float)len;
}

// ---------------------------------------------------------------------------
// Kernel 3: flash attention. One block (4 waves) owns one 16-row q-tile;
// wave w processes key chunks w, w+4, w+8, ... (32 keys each) -> balanced
// split of the causal triangle, 4x the wave parallelism of R1 (whose 1
// wave/SIMD collapsed occupancy to 2.9% and regressed 49->73 us).
// Partials combined via one LDS reduction (no atomics, no global buffers);
// fixed-max softmax (exp(s/sqrt(dk)-8)) keeps partials linear.
//   - b = blockIdx&7 pins each batch to one XCD (K/V = 1 MB -> L2-resident).
//   - per-wave K double-buffer (stride 128); V issued at top of process.
//   - LDS 34 KB -> 4 blocks/CU -> 16 waves/CU (4/SIMD) latency hiding.
// ---------------------------------------------------------------------------
__global__ __launch_bounds__(256) void attn_kernel(
    const __bf16* __restrict__ Qb, const __bf16* __restrict__ Kb,
    const __bf16* __restrict__ Vt, const int* __restrict__ lengths,
    const float* __restrict__ Vmean, float* __restrict__ out)
{
    __shared__ float redO[4][16][132];        // +4 pad: quads land 2-way (free)
    __shared__ float redL[4][16];

    const int b    = blockIdx.x & 7;          // batch -> XCD pin (round-robin)
    const int t    = 127 - (blockIdx.x >> 3); // longest tiles dispatch first
    const int qw   = t * 16;
    const int len  = lengths[b];
    const int tid  = threadIdx.x;
    const int wave = tid >> 6;
    const int lane = tid & 63;
    const int quad = lane >> 4;
    const int l16  = lane & 15;

    if (qw >= len) {                          // fully-padded tile: exact Vmean
        const int row = tid >> 4;
        const int c8  = (tid & 15) * 8;
        float* op = out + (size_t)(b * SS + qw + row) * DKK + c8;
        const float4 v0 = *(const float4*)(Vmean + b * DKK + c8);
        const float4 v1 = *(const float4*)(Vmean + b * DKK + c8 + 4);
        *(float4*)op = v0; *(float4*)(op + 4) = v1;
        return;                               // whole block returns: no barrier
    }

    const int jmax = min(qw + 16, len);       // causal: keys in [0, jmax)
    const __bf16* Qbase = Qb + (size_t)(b * SS + qw) * DKK;
    const __bf16* Kbase = Kb + (size_t)b * SS * DKK;
    const __bf16* Vbase = Vt + (size_t)b * DKK * SS;

    bf16x8 qfrag[4];
#pragma unroll
    for (int cc = 0; cc < 4; ++cc)
        qfrag[cc] = *(const bf16x8*)(Qbase + (size_t)l16 * DKK + cc * 32 + quad * 8);

    floatx4 oacc[8];
#pragma unroll
    for (int nt = 0; nt < 8; ++nt) oacc[nt] = (floatx4){0.f,0.f,0.f,0.f};
    float lsum = 0.f;                         // per-lane, q = l16
    const float scale = 0.08838834764831845f; // 1/sqrt(128)
    const int   iq    = qw + l16;

    auto loadK = [&](bf16x8 (&kf)[2][4], int j0) {
#pragma unroll
        for (int jt = 0; jt < 2; ++jt)
#pragma unroll
            for (int cc = 0; cc < 4; ++cc)
                kf[jt][cc] = *(const bf16x8*)(
                    Kbase + (size_t)(j0 + jt*16 + l16) * DKK + cc*32 + quad*8);
    };
    auto process = [&](const bf16x8 (&kf)[2][4], int j0) {
        bf16x8 vf[8];                          // issue V first: latency hides
#pragma unroll                                 // under QK MFMA + softmax chain
        for (int nt = 0; nt < 8; ++nt)
            vf[nt] = *(const bf16x8*)(Vbase + (size_t)(nt*16 + l16) * SS + j0 + quad*8);

        // S^T[key][q]: A = K-frag (m=key), B = Q-frag (n=q)   (verified R5)
        floatx4 st[2];
#pragma unroll
        for (int jt = 0; jt < 2; ++jt) {
            st[jt] = (floatx4){0.f,0.f,0.f,0.f};
#pragma unroll
            for (int cc = 0; cc < 4; ++cc)
                st[jt] = __builtin_amdgcn_mfma_f32_16x16x32_bf16(
                    kf[jt][cc], qfrag[cc], st[jt], 0, 0, 0);
        }
        int pk[2][2];
#pragma unroll
        for (int jt = 0; jt < 2; ++jt) {
            float p[4];
#pragma unroll
            for (int rr = 0; rr < 4; ++rr) {
                const int j = j0 + jt*16 + quad*4 + rr;
                // j>=len needed: zeroed K rows past len would give exp(-8)
                // and inflate lsum for padded q-rows of partial tiles.
                p[rr] = (j > iq || j >= len) ? 0.f : __expf(st[jt][rr] * scale - 8.f);
                lsum += p[rr];
            }
            pk[jt][0] = pack2(p[0], p[1]);
            pk[jt][1] = pack2(p[2], p[3]);
        }
        // C->A layout via cross-lane pull (verified R5)
        const int a0 = (((quad & 1) << 5) + l16) << 2;
        const int a1 = a0 + 64;
        const int r00 = __builtin_amdgcn_ds_bpermute(a0, pk[0][0]);
        const int r01 = __builtin_amdgcn_ds_bpermute(a0, pk[0][1]);
        const int r02 = __builtin_amdgcn_ds_bpermute(a0, pk[1][0]);
        const int r03 = __builtin_amdgcn_ds_bpermute(a0, pk[1][1]);
        const int r10 = __builtin_amdgcn_ds_bpermute(a1, pk[0][0]);
        const int r11 = __builtin_amdgcn_ds_bpermute(a1, pk[0][1]);
        const int r12 = __builtin_amdgcn_ds_bpermute(a1, pk[1][0]);
        const int r13 = __builtin_amdgcn_ds_bpermute(a1, pk[1][1]);
        const bool hi = quad >= 2;
        union { intx4 i; bf16x8 h; } u;
        u.i = (intx4){ hi ? r02 : r00, hi ? r03 : r01,
                       hi ? r12 : r10, hi ? r13 : r11 };
#pragma unroll
        for (int nt = 0; nt < 8; ++nt)
            oacc[nt] = __builtin_amdgcn_mfma_f32_16x16x32_bf16(u.h, vf[nt], oacc[nt], 0, 0, 0);
    };

    // wave w: chunks w, w+4, w+8, ... (stride 128 keys), double-buffered
    bf16x8 kfA[2][4], kfB[2][4];
    int j0 = wave * 32;
    if (j0 < jmax) {
        loadK(kfA, j0);
        while (true) {
            bool more = (j0 + 128 < jmax);
            if (more) loadK(kfB, j0 + 128);   // prefetch next chunk
            process(kfA, j0);
            j0 += 128;
            if (!more) break;
            more = (j0 + 128 < jmax);
            if (more) loadK(kfA, j0 + 128);
            process(kfB, j0);
            j0 += 128;
            if (!more) break;
        }
    }

    // quad-reduce lsum: every lane holds this wave's row-total for q = l16
    lsum += __shfl_xor(lsum, 16, 64);
    lsum += __shfl_xor(lsum, 32, 64);

    // cross-wave reduction in LDS.  C/D layout: row = quad*4+rr, col = nt*16+l16
#pragma unroll
    for (int nt = 0; nt < 8; ++nt)
#pragma unroll
        for (int rr = 0; rr < 4; ++rr)
            redO[wave][quad*4 + rr][nt*16 + l16] = oacc[nt][rr];
    if (lane < 16) redL[wave][l16] = lsum;
    __syncthreads();

    // cooperative epilogue: 256 threads, 8 cols each
    const int row = tid >> 4;
    const int c8  = (tid & 15) * 8;
    const float lt = redL[0][row] + redL[1][row] + redL[2][row] + redL[3][row];
    const float inv = 1.f / lt;
    float* op = out + (size_t)(b * SS + qw + row) * DKK + c8;
#pragma unroll
    for (int k = 0; k < 8; ++k) {
        const float s = redO[0][row][c8+k] + redO[1][row][c8+k]
                      + redO[2][row][c8+k] + redO[3][row][c8+k];
        op[k] = s * inv;
    }
}

extern "C" void kernel_launch(void* const* d_in, const int* in_sizes, int n_in,
                              void* d_out, int out_size, void* d_ws, size_t ws_size,
                              hipStream_t stream) {
    const float* x   = (const float*)d_in[0];
    const float* ctx = (const float*)d_in[1];
    const float* Wq  = (const float*)d_in[2];
    const float* Wk  = (const float*)d_in[3];
    const float* Wv  = (const float*)d_in[4];
    const int* lengths = (const int*)d_in[5];
    float* out = (float*)d_out;

    char* ws = (char*)d_ws;
    __bf16* Wt = (__bf16*)ws;                          // 768 KB
    __bf16* Qb = (__bf16*)(ws + 786432);               // 4 MB
    __bf16* Kb = (__bf16*)(ws + 786432 + 4194304);     // 4 MB
    __bf16* Vt = (__bf16*)(ws + 786432 + 8388608);     // 4 MB (V^T)
    float*  Vm = (float*) (ws + 786432 + 12582912);    // 4 KB
    // total ~12.8 MB (no Oacc/Lacc/memset needed)

    convw_kernel<<<dim3(64, 3), 256, 0, stream>>>(Wq, Wk, Wv, Wt);
    proj_kernel<<<512, 256, 0, stream>>>(x, ctx, Wt, lengths, Qb, Kb, Vt);
    vmean_kernel<<<64, 256, 0, stream>>>(Vt, lengths, Vm);
    attn_kernel<<<1024, 256, 0, stream>>>(Qb, Kb, Vt, lengths, Vm, out);
}

// Round 4
// 227.267 us; speedup vs baseline: 1.0432x; 1.0321x over previous
//
#include <hip/hip_runtime.h>
#include <hip/hip_bf16.h>

// Problem dims (fixed by setup_inputs)
#define BB 8
#define SS 2048
#define DD 1024
#define DKK 128

using bf16x8  = __attribute__((ext_vector_type(8))) __bf16;
using floatx4 = __attribute__((ext_vector_type(4))) float;
using intx4   = __attribute__((ext_vector_type(4))) int;

// async global->LDS, 16B/lane. LDS dest = wave-uniform base + lane*16 (HW rule).
__device__ __forceinline__ void lds16(const void* g, void* l) {
    __builtin_amdgcn_global_load_lds((const __attribute__((address_space(1))) void*)g,
                                     (__attribute__((address_space(3))) void*)l, 16, 0, 0);
}

__device__ __forceinline__ int pack2(float a, float b) {
    union { __bf16 h; unsigned short u; } ua, ub;
    ua.h = (__bf16)a; ub.h = (__bf16)b;
    return (int)(ua.u | ((unsigned)ub.u << 16));
}

// ---------------------------------------------------------------------------
// Kernel 0: W (fp32 [128][1024]) -> bf16, k-tile-major + 16B-block XOR swizzle
// ---------------------------------------------------------------------------
__global__ __launch_bounds__(256) void convw_kernel(
    const float* __restrict__ Wq, const float* __restrict__ Wk,
    const float* __restrict__ Wv, __bf16* __restrict__ Wt)
{
    const int z = blockIdx.y;
    const float* W = (z == 0) ? Wq : (z == 1) ? Wk : Wv;
    const int t  = blockIdx.x * 256 + threadIdx.x;   // 0..16383
    const int n  = t >> 7;
    const int k0 = (t & 127) * 8;
    float4 f0 = *(const float4*)(W + n * DD + k0);
    float4 f1 = *(const float4*)(W + n * DD + k0 + 4);
    bf16x8 v;
    v[0]=(__bf16)f0.x; v[1]=(__bf16)f0.y; v[2]=(__bf16)f0.z; v[3]=(__bf16)f0.w;
    v[4]=(__bf16)f1.x; v[5]=(__bf16)f1.y; v[6]=(__bf16)f1.z; v[7]=(__bf16)f1.w;
    const int kb  = (k0 >> 3) & 7;
    const int kbs = kb ^ (n & 7);
    *(bf16x8*)(Wt + (size_t)z * 131072 + ((k0 >> 6) * 128 + n) * 64 + kbs * 8) = v;
}

// ---------------------------------------------------------------------------
// Kernel 1: projections (unchanged — isolate this round's variables).
// ---------------------------------------------------------------------------
__global__ __launch_bounds__(256, 2) void proj_kernel(
    const float* __restrict__ x, const float* __restrict__ ctx,
    const __bf16* __restrict__ Wt, const int* __restrict__ lengths,
    __bf16* __restrict__ Qb, __bf16* __restrict__ Kb, __bf16* __restrict__ Vt)
{
    __shared__ __align__(16) __bf16 SH[20992];      // 41984 B
    __bf16* Abuf = SH;                              // 64 x 72 (padded)
    __bf16* Wl0  = SH + 4608;                       // 128 x 64 (swizzled image)
    __bf16* Wl1  = SH + 12800;
    __bf16* T    = SH + 4608;                       // V epilogue overlay, 128 x 72

    const int isV = blockIdx.x >= 256;
    const int m0  = (isV ? blockIdx.x - 256 : blockIdx.x) * 64;
    const int b   = m0 >> 11;
    const int s0  = m0 & (SS - 1);
    const int len = lengths[b];
    if (s0 >= len) return;                          // fully-padded tile

    const int tid  = threadIdx.x;
    const int wave = tid >> 6;
    const int lane = tid & 63;
    const int quad = lane >> 4;
    const int l16  = lane & 15;
    const int wm   = wave >> 1;
    const int wn   = wave & 1;

    const float*  A  = isV ? x : ctx;
    const __bf16* W0 = isV ? (Wt + 262144) : Wt;
    const __bf16* W1 = Wt + 131072;

    const int r    = tid >> 2;
    const int kseg = (tid & 3) * 16;
    const float* Ab = A + (size_t)(m0 + r) * DD + kseg;

    floatx4 acc[2][2][4];
#pragma unroll
    for (int m_ = 0; m_ < 2; ++m_)
#pragma unroll
        for (int i = 0; i < 2; ++i)
#pragma unroll
            for (int j = 0; j < 4; ++j) acc[m_][i][j] = (floatx4){0.f,0.f,0.f,0.f};

    float4 pf[4];
#pragma unroll
    for (int i = 0; i < 4; ++i) pf[i] = *(const float4*)(Ab + i * 4);

    for (int t = 0; t < 16; ++t) {
        __syncthreads();
        {
            bf16x8 c0, c1;
            c0[0]=(__bf16)pf[0].x; c0[1]=(__bf16)pf[0].y; c0[2]=(__bf16)pf[0].z; c0[3]=(__bf16)pf[0].w;
            c0[4]=(__bf16)pf[1].x; c0[5]=(__bf16)pf[1].y; c0[6]=(__bf16)pf[1].z; c0[7]=(__bf16)pf[1].w;
            c1[0]=(__bf16)pf[2].x; c1[1]=(__bf16)pf[2].y; c1[2]=(__bf16)pf[2].z; c1[3]=(__bf16)pf[2].w;
            c1[4]=(__bf16)pf[3].x; c1[5]=(__bf16)pf[3].y; c1[6]=(__bf16)pf[3].z; c1[7]=(__bf16)pf[3].w;
            *(bf16x8*)&Abuf[r * 72 + kseg]     = c0;
            *(bf16x8*)&Abuf[r * 72 + kseg + 8] = c1;
        }
#pragma unroll
        for (int i = 0; i < 4; ++i) {
            const int c = wave * 4 + i;
            lds16(W0 + (size_t)t * 8192 + c * 512 + lane * 8, Wl0 + c * 512);
            if (!isV)
                lds16(W1 + (size_t)t * 8192 + c * 512 + lane * 8, Wl1 + c * 512);
        }
        if (t < 15) {
            const float* ap = Ab + (t + 1) * 64;
#pragma unroll
            for (int i = 0; i < 4; ++i) pf[i] = *(const float4*)(ap + i * 4);
        }
        __syncthreads();

#pragma unroll
        for (int kh = 0; kh < 2; ++kh) {
            bf16x8 af[2];
#pragma unroll
            for (int mt = 0; mt < 2; ++mt)
                af[mt] = *(const bf16x8*)&Abuf[(wm*32 + mt*16 + l16) * 72 + kh*32 + quad*8];
            const int kb = kh * 4 + quad;
#pragma unroll
            for (int nt = 0; nt < 4; ++nt) {
                const int n = wn * 64 + nt * 16 + l16;
                const int off = n * 64 + ((kb ^ (n & 7)) << 3);
                bf16x8 w0 = *(const bf16x8*)&Wl0[off];
#pragma unroll
                for (int mt = 0; mt < 2; ++mt)
                    acc[0][mt][nt] = __builtin_amdgcn_mfma_f32_16x16x32_bf16(af[mt], w0, acc[0][mt][nt], 0, 0, 0);
                if (!isV) {
                    bf16x8 w1 = *(const bf16x8*)&Wl1[off];
#pragma unroll
                    for (int mt = 0; mt < 2; ++mt)
                        acc[1][mt][nt] = __builtin_amdgcn_mfma_f32_16x16x32_bf16(af[mt], w1, acc[1][mt][nt], 0, 0, 0);
                }
            }
        }
    }

    if (!isV) {
#pragma unroll
        for (int mt = 0; mt < 2; ++mt)
#pragma unroll
            for (int rr = 0; rr < 4; ++rr) {
                const int row = m0 + wm*32 + mt*16 + quad*4 + rr;
                const float mk = ((row & (SS - 1)) < len) ? 1.f : 0.f;
#pragma unroll
                for (int nt = 0; nt < 4; ++nt) {
                    const int col = wn*64 + nt*16 + l16;
                    Qb[(size_t)row * DKK + col] = (__bf16)(acc[0][mt][nt][rr] * mk);
                    Kb[(size_t)row * DKK + col] = (__bf16)(acc[1][mt][nt][rr] * mk);
                }
            }
    } else {
        __syncthreads();
#pragma unroll
        for (int mt = 0; mt < 2; ++mt)
#pragma unroll
            for (int nt = 0; nt < 4; ++nt)
#pragma unroll
                for (int rr = 0; rr < 4; ++rr) {
                    const int s = wm*32 + mt*16 + quad*4 + rr;
                    const int n = wn*64 + nt*16 + l16;
                    const float mk = (s0 + s < len) ? 1.f : 0.f;
                    T[n * 72 + s] = (__bf16)(acc[0][mt][nt][rr] * mk);
                }
        __syncthreads();
        const int n = tid >> 1, h = tid & 1;
        __bf16* dst = Vt + (size_t)b * DKK * SS + (size_t)n * SS + s0 + h * 32;
#pragma unroll
        for (int i = 0; i < 4; ++i)
            *(bf16x8*)(dst + i * 8) = *(const bf16x8*)&T[n * 72 + h * 32 + i * 8];
    }
}

// ---------------------------------------------------------------------------
// Kernel 2: per-batch column mean of V (exact output for padded q-rows).
// ---------------------------------------------------------------------------
__global__ __launch_bounds__(256) void vmean_kernel(
    const __bf16* __restrict__ Vt, const int* __restrict__ lengths,
    float* __restrict__ Vmean)
{
    const int b   = blockIdx.x >> 3;
    const int g3  = blockIdx.x & 7;
    const int len = lengths[b];
    const int tid = threadIdx.x;
    const int n   = g3 * 16 + (tid >> 4);
    const int sl  = (tid & 15) * 128;                 // this thread's 128-elem span
    const __bf16* src = Vt + (size_t)b * DKK * SS + (size_t)n * SS + sl;
    float s = 0.f;
#pragma unroll
    for (int i = 0; i < 16; ++i) {
        bf16x8 v = *(const bf16x8*)(src + i * 8);
#pragma unroll
        for (int j = 0; j < 8; ++j)
            s += (sl + i * 8 + j < len) ? (float)v[j] : 0.f;
    }
#pragma unroll
    for (int off = 1; off < 16; off <<= 1)
        s += __shfl_xor(s, off, 64);
    if ((tid & 15) == 0) Vmean[b * DKK + n] = s / (float)len;
}

// ---------------------------------------------------------------------------
// Kernel 3: flash attention. Block = 64 q-rows x 4 waves (wave w = q-subtile
// w, 16 rows). ALL waves share one 64-key chunk staged in LDS (K 16KB +
// V 16KB, double-buffered = 64 KB) via global_load_lds with pre-swizzled
// global source (linear LDS dest + XOR-swizzled src + swizzled ds_read:
// rule 21). One barrier per chunk; its implicit vmcnt-drain lands after a
// full chunk of compute -> staging latency hidden. 4x K/V dedup vs R2.
// No cross-wave reduction: each wave writes its own 16 rows. Fixed-max
// softmax (exp(s/sqrt(dk)-8)) as verified in R0-R2.
// R2 failure fixed: L2 latency no longer on the per-chunk critical path
// (VGPR=120 had defeated the register prefetch -> ~4000 cy/chunk).
// ---------------------------------------------------------------------------
__global__ __launch_bounds__(256) void attn_kernel(
    const __bf16* __restrict__ Qb, const __bf16* __restrict__ Kb,
    const __bf16* __restrict__ Vt, const int* __restrict__ lengths,
    const float* __restrict__ Vmean, float* __restrict__ out)
{
    __shared__ __align__(16) __bf16 KB[2 * 8192];   // 2 x [64 rows][128] 32 KB
    __shared__ __align__(16) __bf16 VB[2 * 8192];   // 2 x [128 rows][64] 32 KB

    const int b    = blockIdx.x & 7;          // batch -> XCD pin (round-robin)
    const int qt   = 31 - (blockIdx.x >> 3);  // longest tiles first
    const int qw   = qt * 64;
    const int len  = lengths[b];
    const int tid  = threadIdx.x;
    const int wave = tid >> 6;
    const int lane = tid & 63;
    const int quad = lane >> 4;
    const int l16  = lane & 15;

    if (qw >= len) {                          // fully-padded tile: exact Vmean
        const int c8 = (tid & 15) * 8;
        const float4 v0 = *(const float4*)(Vmean + b * DKK + c8);
        const float4 v1 = *(const float4*)(Vmean + b * DKK + c8 + 4);
#pragma unroll
        for (int pass = 0; pass < 4; ++pass) {
            const int row = pass * 16 + (tid >> 4);
            float* op = out + (size_t)(b * SS + qw + row) * DKK + c8;
            *(float4*)op = v0; *(float4*)(op + 4) = v1;
        }
        return;                               // whole block returns: no barrier
    }

    const int jmax = min(qw + 64, len);       // causal: keys in [0, jmax)
    const int nc   = (jmax + 63) >> 6;        // 64-key chunks
    const __bf16* Kbase = Kb + (size_t)b * SS * DKK;
    const __bf16* Vbase = Vt + (size_t)b * DKK * SS;

    // Q fragments for this wave's 16 rows
    bf16x8 qfrag[4];
    {
        const __bf16* Qbase = Qb + (size_t)(b * SS + qw + wave * 16) * DKK;
#pragma unroll
        for (int cc = 0; cc < 4; ++cc)
            qfrag[cc] = *(const bf16x8*)(Qbase + (size_t)l16 * DKK + cc * 32 + quad * 8);
    }

    floatx4 oacc[8];
#pragma unroll
    for (int nt = 0; nt < 8; ++nt) oacc[nt] = (floatx4){0.f,0.f,0.f,0.f};
    float lsum = 0.f;                         // per-lane, q = l16
    const float scale = 0.08838834764831845f; // 1/sqrt(128)
    const int   iq    = qw + wave * 16 + l16;
    const int   sw7   = l16 & 7;              // read-side swizzle key

    // Stage K chunk rows [j0, j0+64): LDS slot (row, blk16B) holds global
    // block (blk ^ (row&7)). Call c stages rows c*4..c*4+3 (1 KB).
    auto stageK = [&](int buf, int j0) {
#pragma unroll
        for (int i = 0; i < 4; ++i) {
            const int c   = wave * 4 + i;           // 0..15
            const int row = c * 4 + quad;           // 0..63
            const int sb  = l16 ^ (row & 7);        // inverse-swizzled src blk
            lds16(Kbase + (size_t)(j0 + row) * DKK + sb * 8,
                  KB + buf * 8192 + c * 512);
        }
    };
    // Stage V chunk (dk rows x 64 keys): call c stages dk rows c*8..c*8+7.
    auto stageV = [&](int buf, int j0) {
#pragma unroll
        for (int i = 0; i < 4; ++i) {
            const int c   = wave * 4 + i;           // 0..15
            const int row = c * 8 + (lane >> 3);    // 0..127
            const int sb  = (lane & 7) ^ (row & 7);
            lds16(Vbase + (size_t)row * SS + j0 + sb * 8,
                  VB + buf * 8192 + c * 512);
        }
    };

    auto process = [&](int buf, int j0) {
        const int kbas = buf * 8192;
        // S^T[key][q]: A = K-frag (m=key), B = Q-frag (n=q)   (verified R2)
        floatx4 st[4];
#pragma unroll
        for (int jt = 0; jt < 4; ++jt) {
            st[jt] = (floatx4){0.f,0.f,0.f,0.f};
#pragma unroll
            for (int cc = 0; cc < 4; ++cc) {
                bf16x8 kf = *(const bf16x8*)(
                    KB + kbas + (jt*16 + l16) * 128 + (((cc*4 + quad) ^ sw7) * 8));
                st[jt] = __builtin_amdgcn_mfma_f32_16x16x32_bf16(
                    kf, qfrag[cc], st[jt], 0, 0, 0);
            }
        }
        int pk[4][2];
#pragma unroll
        for (int jt = 0; jt < 4; ++jt) {
            float p[4];
#pragma unroll
            for (int rr = 0; rr < 4; ++rr) {
                const int j = j0 + jt*16 + quad*4 + rr;
                // j>=len: zeroed K rows past len would give exp(-8) and
                // inflate lsum for padded q-rows of partial tiles.
                p[rr] = (j > iq || j >= len) ? 0.f : __expf(st[jt][rr] * scale - 8.f);
                lsum += p[rr];
            }
            pk[jt][0] = pack2(p[0], p[1]);
            pk[jt][1] = pack2(p[2], p[3]);
        }
        // C->A layout via cross-lane pull (verified R2); frag f = keys f*32..+31
        const int a0 = (((quad & 1) << 5) + l16) << 2;
        const int a1 = a0 + 64;
#pragma unroll
        for (int f = 0; f < 2; ++f) {
            const int r00 = __builtin_amdgcn_ds_bpermute(a0, pk[2*f  ][0]);
            const int r01 = __builtin_amdgcn_ds_bpermute(a0, pk[2*f  ][1]);
            const int r02 = __builtin_amdgcn_ds_bpermute(a0, pk[2*f+1][0]);
            const int r03 = __builtin_amdgcn_ds_bpermute(a0, pk[2*f+1][1]);
            const int r10 = __builtin_amdgcn_ds_bpermute(a1, pk[2*f  ][0]);
            const int r11 = __builtin_amdgcn_ds_bpermute(a1, pk[2*f  ][1]);
            const int r12 = __builtin_amdgcn_ds_bpermute(a1, pk[2*f+1][0]);
            const int r13 = __builtin_amdgcn_ds_bpermute(a1, pk[2*f+1][1]);
            const bool hi = quad >= 2;
            union { intx4 i; bf16x8 h; } u;
            u.i = (intx4){ hi ? r02 : r00, hi ? r03 : r01,
                           hi ? r12 : r10, hi ? r13 : r11 };
#pragma unroll
            for (int nt = 0; nt < 8; ++nt) {
                bf16x8 vf = *(const bf16x8*)(
                    VB + kbas + (nt*16 + l16) * 64 + (((f*4 + quad) ^ sw7) * 8));
                oacc[nt] = __builtin_amdgcn_mfma_f32_16x16x32_bf16(
                    u.h, vf, oacc[nt], 0, 0, 0);
            }
        }
    };

    // chunk loop: stage(next) issued before compute(cur); the barrier's
    // implicit vmcnt/lgkm drain completes next-chunk staging after a full
    // chunk of compute has hidden its latency.
    stageK(0, 0); stageV(0, 0);
    __syncthreads();
    for (int c = 0; c < nc; ++c) {
        const int cur = c & 1;
        if (c + 1 < nc) { stageK(cur ^ 1, (c + 1) * 64); stageV(cur ^ 1, (c + 1) * 64); }
        process(cur, c * 64);
        __syncthreads();
    }

    // quad-reduce lsum: every lane holds total for q-row = l16
    lsum += __shfl_xor(lsum, 16, 64);
    lsum += __shfl_xor(lsum, 32, 64);
    float inv[4];
#pragma unroll
    for (int rr = 0; rr < 4; ++rr)
        inv[rr] = 1.f / __shfl(lsum, quad * 4 + rr, 64);
    // C/D layout: row(q) = quad*4+rr, col(dk) = nt*16+l16
#pragma unroll
    for (int nt = 0; nt < 8; ++nt)
#pragma unroll
        for (int rr = 0; rr < 4; ++rr)
            out[(size_t)(b * SS + qw + wave*16 + quad*4 + rr) * DKK + nt*16 + l16] =
                oacc[nt][rr] * inv[rr];
}

extern "C" void kernel_launch(void* const* d_in, const int* in_sizes, int n_in,
                              void* d_out, int out_size, void* d_ws, size_t ws_size,
                              hipStream_t stream) {
    const float* x   = (const float*)d_in[0];
    const float* ctx = (const float*)d_in[1];
    const float* Wq  = (const float*)d_in[2];
    const float* Wk  = (const float*)d_in[3];
    const float* Wv  = (const float*)d_in[4];
    const int* lengths = (const int*)d_in[5];
    float* out = (float*)d_out;

    char* ws = (char*)d_ws;
    __bf16* Wt = (__bf16*)ws;                          // 768 KB
    __bf16* Qb = (__bf16*)(ws + 786432);               // 4 MB
    __bf16* Kb = (__bf16*)(ws + 786432 + 4194304);     // 4 MB
    __bf16* Vt = (__bf16*)(ws + 786432 + 8388608);     // 4 MB (V^T)
    float*  Vm = (float*) (ws + 786432 + 12582912);    // 4 KB

    convw_kernel<<<dim3(64, 3), 256, 0, stream>>>(Wq, Wk, Wv, Wt);
    proj_kernel<<<512, 256, 0, stream>>>(x, ctx, Wt, lengths, Qb, Kb, Vt);
    vmean_kernel<<<64, 256, 0, stream>>>(Vt, lengths, Vm);
    attn_kernel<<<256, 256, 0, stream>>>(Qb, Kb, Vt, lengths, Vm, out);
}

// Round 5
// 215.465 us; speedup vs baseline: 1.1004x; 1.0548x over previous
//
#include <hip/hip_runtime.h>
#include <hip/hip_bf16.h>

// Problem dims (fixed by setup_inputs)
#define BB 8
#define SS 2048
#define DD 1024
#define DKK 128

using bf16x8  = __attribute__((ext_vector_type(8))) __bf16;
using floatx4 = __attribute__((ext_vector_type(4))) float;
using intx4   = __attribute__((ext_vector_type(4))) int;

// async global->LDS, 16B/lane. LDS dest = wave-uniform base + lane*16 (HW rule).
__device__ __forceinline__ void lds16(const void* g, void* l) {
    __builtin_amdgcn_global_load_lds((const __attribute__((address_space(1))) void*)g,
                                     (__attribute__((address_space(3))) void*)l, 16, 0, 0);
}

__device__ __forceinline__ int pack2(float a, float b) {
    union { __bf16 h; unsigned short u; } ua, ub;
    ua.h = (__bf16)a; ub.h = (__bf16)b;
    return (int)(ua.u | ((unsigned)ub.u << 16));
}

// ---------------------------------------------------------------------------
// Kernel 0: W (fp32 [128][1024]) -> bf16, k-tile-major + 16B-block XOR swizzle
// ---------------------------------------------------------------------------
__global__ __launch_bounds__(256) void convw_kernel(
    const float* __restrict__ Wq, const float* __restrict__ Wk,
    const float* __restrict__ Wv, __bf16* __restrict__ Wt)
{
    const int z = blockIdx.y;
    const float* W = (z == 0) ? Wq : (z == 1) ? Wk : Wv;
    const int t  = blockIdx.x * 256 + threadIdx.x;   // 0..16383
    const int n  = t >> 7;
    const int k0 = (t & 127) * 8;
    float4 f0 = *(const float4*)(W + n * DD + k0);
    float4 f1 = *(const float4*)(W + n * DD + k0 + 4);
    bf16x8 v;
    v[0]=(__bf16)f0.x; v[1]=(__bf16)f0.y; v[2]=(__bf16)f0.z; v[3]=(__bf16)f0.w;
    v[4]=(__bf16)f1.x; v[5]=(__bf16)f1.y; v[6]=(__bf16)f1.z; v[7]=(__bf16)f1.w;
    const int kb  = (k0 >> 3) & 7;
    const int kbs = kb ^ (n & 7);
    *(bf16x8*)(Wt + (size_t)z * 131072 + ((k0 >> 6) * 128 + n) * 64 + kbs * 8) = v;
}

// ---------------------------------------------------------------------------
// Kernel 1: projections (unchanged — isolate this round's variables).
// ---------------------------------------------------------------------------
__global__ __launch_bounds__(256, 2) void proj_kernel(
    const float* __restrict__ x, const float* __restrict__ ctx,
    const __bf16* __restrict__ Wt, const int* __restrict__ lengths,
    __bf16* __restrict__ Qb, __bf16* __restrict__ Kb, __bf16* __restrict__ Vt)
{
    __shared__ __align__(16) __bf16 SH[20992];      // 41984 B
    __bf16* Abuf = SH;                              // 64 x 72 (padded)
    __bf16* Wl0  = SH + 4608;                       // 128 x 64 (swizzled image)
    __bf16* Wl1  = SH + 12800;
    __bf16* T    = SH + 4608;                       // V epilogue overlay, 128 x 72

    const int isV = blockIdx.x >= 256;
    const int m0  = (isV ? blockIdx.x - 256 : blockIdx.x) * 64;
    const int b   = m0 >> 11;
    const int s0  = m0 & (SS - 1);
    const int len = lengths[b];
    if (s0 >= len) return;                          // fully-padded tile

    const int tid  = threadIdx.x;
    const int wave = tid >> 6;
    const int lane = tid & 63;
    const int quad = lane >> 4;
    const int l16  = lane & 15;
    const int wm   = wave >> 1;
    const int wn   = wave & 1;

    const float*  A  = isV ? x : ctx;
    const __bf16* W0 = isV ? (Wt + 262144) : Wt;
    const __bf16* W1 = Wt + 131072;

    const int r    = tid >> 2;
    const int kseg = (tid & 3) * 16;
    const float* Ab = A + (size_t)(m0 + r) * DD + kseg;

    floatx4 acc[2][2][4];
#pragma unroll
    for (int m_ = 0; m_ < 2; ++m_)
#pragma unroll
        for (int i = 0; i < 2; ++i)
#pragma unroll
            for (int j = 0; j < 4; ++j) acc[m_][i][j] = (floatx4){0.f,0.f,0.f,0.f};

    float4 pf[4];
#pragma unroll
    for (int i = 0; i < 4; ++i) pf[i] = *(const float4*)(Ab + i * 4);

    for (int t = 0; t < 16; ++t) {
        __syncthreads();
        {
            bf16x8 c0, c1;
            c0[0]=(__bf16)pf[0].x; c0[1]=(__bf16)pf[0].y; c0[2]=(__bf16)pf[0].z; c0[3]=(__bf16)pf[0].w;
            c0[4]=(__bf16)pf[1].x; c0[5]=(__bf16)pf[1].y; c0[6]=(__bf16)pf[1].z; c0[7]=(__bf16)pf[1].w;
            c1[0]=(__bf16)pf[2].x; c1[1]=(__bf16)pf[2].y; c1[2]=(__bf16)pf[2].z; c1[3]=(__bf16)pf[2].w;
            c1[4]=(__bf16)pf[3].x; c1[5]=(__bf16)pf[3].y; c1[6]=(__bf16)pf[3].z; c1[7]=(__bf16)pf[3].w;
            *(bf16x8*)&Abuf[r * 72 + kseg]     = c0;
            *(bf16x8*)&Abuf[r * 72 + kseg + 8] = c1;
        }
#pragma unroll
        for (int i = 0; i < 4; ++i) {
            const int c = wave * 4 + i;
            lds16(W0 + (size_t)t * 8192 + c * 512 + lane * 8, Wl0 + c * 512);
            if (!isV)
                lds16(W1 + (size_t)t * 8192 + c * 512 + lane * 8, Wl1 + c * 512);
        }
        if (t < 15) {
            const float* ap = Ab + (t + 1) * 64;
#pragma unroll
            for (int i = 0; i < 4; ++i) pf[i] = *(const float4*)(ap + i * 4);
        }
        __syncthreads();

#pragma unroll
        for (int kh = 0; kh < 2; ++kh) {
            bf16x8 af[2];
#pragma unroll
            for (int mt = 0; mt < 2; ++mt)
                af[mt] = *(const bf16x8*)&Abuf[(wm*32 + mt*16 + l16) * 72 + kh*32 + quad*8];
            const int kb = kh * 4 + quad;
#pragma unroll
            for (int nt = 0; nt < 4; ++nt) {
                const int n = wn * 64 + nt * 16 + l16;
                const int off = n * 64 + ((kb ^ (n & 7)) << 3);
                bf16x8 w0 = *(const bf16x8*)&Wl0[off];
#pragma unroll
                for (int mt = 0; mt < 2; ++mt)
                    acc[0][mt][nt] = __builtin_amdgcn_mfma_f32_16x16x32_bf16(af[mt], w0, acc[0][mt][nt], 0, 0, 0);
                if (!isV) {
                    bf16x8 w1 = *(const bf16x8*)&Wl1[off];
#pragma unroll
                    for (int mt = 0; mt < 2; ++mt)
                        acc[1][mt][nt] = __builtin_amdgcn_mfma_f32_16x16x32_bf16(af[mt], w1, acc[1][mt][nt], 0, 0, 0);
                }
            }
        }
    }

    if (!isV) {
#pragma unroll
        for (int mt = 0; mt < 2; ++mt)
#pragma unroll
            for (int rr = 0; rr < 4; ++rr) {
                const int row = m0 + wm*32 + mt*16 + quad*4 + rr;
                const float mk = ((row & (SS - 1)) < len) ? 1.f : 0.f;
#pragma unroll
                for (int nt = 0; nt < 4; ++nt) {
                    const int col = wn*64 + nt*16 + l16;
                    Qb[(size_t)row * DKK + col] = (__bf16)(acc[0][mt][nt][rr] * mk);
                    Kb[(size_t)row * DKK + col] = (__bf16)(acc[1][mt][nt][rr] * mk);
                }
            }
    } else {
        __syncthreads();
#pragma unroll
        for (int mt = 0; mt < 2; ++mt)
#pragma unroll
            for (int nt = 0; nt < 4; ++nt)
#pragma unroll
                for (int rr = 0; rr < 4; ++rr) {
                    const int s = wm*32 + mt*16 + quad*4 + rr;
                    const int n = wn*64 + nt*16 + l16;
                    const float mk = (s0 + s < len) ? 1.f : 0.f;
                    T[n * 72 + s] = (__bf16)(acc[0][mt][nt][rr] * mk);
                }
        __syncthreads();
        const int n = tid >> 1, h = tid & 1;
        __bf16* dst = Vt + (size_t)b * DKK * SS + (size_t)n * SS + s0 + h * 32;
#pragma unroll
        for (int i = 0; i < 4; ++i)
            *(bf16x8*)(dst + i * 8) = *(const bf16x8*)&T[n * 72 + h * 32 + i * 8];
    }
}

// ---------------------------------------------------------------------------
// Kernel 2: per-batch column mean of V (exact output for padded q-rows).
// ---------------------------------------------------------------------------
__global__ __launch_bounds__(256) void vmean_kernel(
    const __bf16* __restrict__ Vt, const int* __restrict__ lengths,
    float* __restrict__ Vmean)
{
    const int b   = blockIdx.x >> 3;
    const int g3  = blockIdx.x & 7;
    const int len = lengths[b];
    const int tid = threadIdx.x;
    const int n   = g3 * 16 + (tid >> 4);
    const int sl  = (tid & 15) * 128;                 // this thread's 128-elem span
    const __bf16* src = Vt + (size_t)b * DKK * SS + (size_t)n * SS + sl;
    float s = 0.f;
#pragma unroll
    for (int i = 0; i < 16; ++i) {
        bf16x8 v = *(const bf16x8*)(src + i * 8);
#pragma unroll
        for (int j = 0; j < 8; ++j)
            s += (sl + i * 8 + j < len) ? (float)v[j] : 0.f;
    }
#pragma unroll
    for (int off = 1; off < 16; off <<= 1)
        s += __shfl_xor(s, off, 64);
    if ((tid & 15) == 0) Vmean[b * DKK + n] = s / (float)len;
}

// ---------------------------------------------------------------------------
// Kernel 3: flash attention.
// R3 failure: grid 256 = 1 block/CU = 1 wave/SIMD; makespan = longest block's
// 32 fully-latency-exposed chunks (~4700 cy each vs ~1300 pipelined).
// Now: block = 32 q-rows, grid 512 (2 blocks/CU, long tiles pair with short);
// wave = (sub-tile, key-half): each wave does 16q x 32keys per 64-key chunk,
// all 4 waves share the staged chunk (K 16KB + V 16KB, dbuf 64 KB).
// Per-wave chain per barrier interval halves; 2 waves/SIMD overlap the rest.
// End: 2-way LDS reduce per sub-tile (no atomics). Staging swizzles, QK/PV
// fragment layouts, bpermute C->A shuffle, fixed-max softmax all verbatim
// from the R3/R2 versions (harness-verified).
// ---------------------------------------------------------------------------
__global__ __launch_bounds__(256) void attn_kernel(
    const __bf16* __restrict__ Qb, const __bf16* __restrict__ Kb,
    const __bf16* __restrict__ Vt, const int* __restrict__ lengths,
    const float* __restrict__ Vmean, float* __restrict__ out)
{
    __shared__ __align__(16) __bf16 KB[2 * 8192];   // 2 x [64 keys][128] 32 KB
    __shared__ __align__(16) __bf16 VB[2 * 8192];   // 2 x [128 dk][64 keys] 32 KB

    const int b    = blockIdx.x & 7;          // batch -> XCD pin (round-robin)
    const int qt   = 63 - (blockIdx.x >> 3);  // longest tiles dispatched first
    const int qw   = qt * 32;
    const int len  = lengths[b];
    const int tid  = threadIdx.x;
    const int wave = tid >> 6;
    const int lane = tid & 63;
    const int quad = lane >> 4;
    const int l16  = lane & 15;
    const int sub  = wave >> 1;               // q-subtile (16 rows)
    const int half = wave & 1;                // key half (32 keys)

    if (qw >= len) {                          // fully-padded tile: exact Vmean
        const int c8 = (tid & 15) * 8;
        const float4 v0 = *(const float4*)(Vmean + b * DKK + c8);
        const float4 v1 = *(const float4*)(Vmean + b * DKK + c8 + 4);
#pragma unroll
        for (int pass = 0; pass < 2; ++pass) {
            const int row = pass * 16 + (tid >> 4);
            float* op = out + (size_t)(b * SS + qw + row) * DKK + c8;
            *(float4*)op = v0; *(float4*)(op + 4) = v1;
        }
        return;                               // whole block returns: no barrier
    }

    const int jmax = min(qw + 32, len);       // causal: keys in [0, jmax)
    const int nc   = (jmax + 63) >> 6;        // 64-key chunks
    const __bf16* Kbase = Kb + (size_t)b * SS * DKK;
    const __bf16* Vbase = Vt + (size_t)b * DKK * SS;

    // Q fragments for this wave's 16 rows
    bf16x8 qfrag[4];
    {
        const __bf16* Qbase = Qb + (size_t)(b * SS + qw + sub * 16) * DKK;
#pragma unroll
        for (int cc = 0; cc < 4; ++cc)
            qfrag[cc] = *(const bf16x8*)(Qbase + (size_t)l16 * DKK + cc * 32 + quad * 8);
    }

    floatx4 oacc[8];
#pragma unroll
    for (int nt = 0; nt < 8; ++nt) oacc[nt] = (floatx4){0.f,0.f,0.f,0.f};
    float lsum = 0.f;                         // per-lane, q = l16 (this half)
    const float scale = 0.08838834764831845f; // 1/sqrt(128)
    const int   iq    = qw + sub * 16 + l16;
    const int   sw7   = l16 & 7;              // read-side swizzle key

    // Stage K chunk rows [j0, j0+64): LDS slot (row, blk16B) holds global
    // block (blk ^ (row&7)). Call c stages rows c*4..c*4+3 (1 KB). (R3 vrb.)
    auto stageK = [&](int buf, int j0) {
#pragma unroll
        for (int i = 0; i < 4; ++i) {
            const int c   = wave * 4 + i;           // 0..15
            const int row = c * 4 + quad;           // 0..63
            const int sb  = l16 ^ (row & 7);        // inverse-swizzled src blk
            lds16(Kbase + (size_t)(j0 + row) * DKK + sb * 8,
                  KB + buf * 8192 + c * 512);
        }
    };
    // Stage V chunk (dk rows x 64 keys): call c stages dk rows c*8..c*8+7.
    auto stageV = [&](int buf, int j0) {
#pragma unroll
        for (int i = 0; i < 4; ++i) {
            const int c   = wave * 4 + i;           // 0..15
            const int row = c * 8 + (lane >> 3);    // 0..127
            const int sb  = (lane & 7) ^ (row & 7);
            lds16(Vbase + (size_t)row * SS + j0 + sb * 8,
                  VB + buf * 8192 + c * 512);
        }
    };

    auto process = [&](int buf, int j0) {
        const int kbas = buf * 8192;
        // S^T[key][q] over this wave's 32-key half: A = K-frag, B = Q-frag
        floatx4 st[2];
#pragma unroll
        for (int jt = 0; jt < 2; ++jt) {
            st[jt] = (floatx4){0.f,0.f,0.f,0.f};
#pragma unroll
            for (int cc = 0; cc < 4; ++cc) {
                bf16x8 kf = *(const bf16x8*)(
                    KB + kbas + ((half*2 + jt)*16 + l16) * 128 + (((cc*4 + quad) ^ sw7) * 8));
                st[jt] = __builtin_amdgcn_mfma_f32_16x16x32_bf16(
                    kf, qfrag[cc], st[jt], 0, 0, 0);
            }
        }
        int pk[2][2];
#pragma unroll
        for (int jt = 0; jt < 2; ++jt) {
            float p[4];
#pragma unroll
            for (int rr = 0; rr < 4; ++rr) {
                const int j = j0 + half*32 + jt*16 + quad*4 + rr;
                // j>=len: zeroed K rows past len would give exp(-8) and
                // inflate lsum for padded q-rows of partial tiles.
                p[rr] = (j > iq || j >= len) ? 0.f : __expf(st[jt][rr] * scale - 8.f);
                lsum += p[rr];
            }
            pk[jt][0] = pack2(p[0], p[1]);
            pk[jt][1] = pack2(p[2], p[3]);
        }
        // C->A layout via cross-lane pull (verbatim R2, harness-verified)
        const int a0 = (((quad & 1) << 5) + l16) << 2;
        const int a1 = a0 + 64;
        const int r00 = __builtin_amdgcn_ds_bpermute(a0, pk[0][0]);
        const int r01 = __builtin_amdgcn_ds_bpermute(a0, pk[0][1]);
        const int r02 = __builtin_amdgcn_ds_bpermute(a0, pk[1][0]);
        const int r03 = __builtin_amdgcn_ds_bpermute(a0, pk[1][1]);
        const int r10 = __builtin_amdgcn_ds_bpermute(a1, pk[0][0]);
        const int r11 = __builtin_amdgcn_ds_bpermute(a1, pk[0][1]);
        const int r12 = __builtin_amdgcn_ds_bpermute(a1, pk[1][0]);
        const int r13 = __builtin_amdgcn_ds_bpermute(a1, pk[1][1]);
        const bool hi = quad >= 2;
        union { intx4 i; bf16x8 h; } u;
        u.i = (intx4){ hi ? r02 : r00, hi ? r03 : r01,
                       hi ? r12 : r10, hi ? r13 : r11 };
#pragma unroll
        for (int nt = 0; nt < 8; ++nt) {
            bf16x8 vf = *(const bf16x8*)(
                VB + kbas + (nt*16 + l16) * 64 + (((half*4 + quad) ^ sw7) * 8));
            oacc[nt] = __builtin_amdgcn_mfma_f32_16x16x32_bf16(
                u.h, vf, oacc[nt], 0, 0, 0);
        }
    };

    // chunk loop: stage(next) issued before compute(cur); the barrier's
    // implicit vmcnt/lgkm drain lands after a full chunk of compute.
    stageK(0, 0); stageV(0, 0);
    __syncthreads();
    for (int c = 0; c < nc; ++c) {
        const int cur = c & 1;
        if (c + 1 < nc) { stageK(cur ^ 1, (c + 1) * 64); stageV(cur ^ 1, (c + 1) * 64); }
        process(cur, c * 64);
        __syncthreads();
    }

    // quad-reduce lsum: every lane holds this wave's half-total for q = l16
    lsum += __shfl_xor(lsum, 16, 64);
    lsum += __shfl_xor(lsum, 32, 64);

    // 2-way cross-wave reduce per sub-tile (overlay on KB/VB after barrier)
    float* Ored = (float*)KB;                 // 2 x [16][128] f32 = 16 KB
    float* Lred = (float*)VB;                 // 2 x [16] f32
    if (half) {
#pragma unroll
        for (int nt = 0; nt < 8; ++nt)
#pragma unroll
            for (int rr = 0; rr < 4; ++rr)
                Ored[sub*2048 + (quad*4 + rr)*128 + nt*16 + l16] = oacc[nt][rr];
        if (lane < 16) Lred[sub*16 + l16] = lsum;
    }
    __syncthreads();
    if (!half) {
        const float lt = lsum + Lred[sub*16 + l16];   // row-total for q = l16
        float inv[4];
#pragma unroll
        for (int rr = 0; rr < 4; ++rr)
            inv[rr] = 1.f / __shfl(lt, quad * 4 + rr, 64);
        // C/D layout: row(q) = quad*4+rr, col(dk) = nt*16+l16
#pragma unroll
        for (int nt = 0; nt < 8; ++nt)
#pragma unroll
            for (int rr = 0; rr < 4; ++rr)
                out[(size_t)(b * SS + qw + sub*16 + quad*4 + rr) * DKK + nt*16 + l16] =
                    (oacc[nt][rr] + Ored[sub*2048 + (quad*4 + rr)*128 + nt*16 + l16]) * inv[rr];
    }
}

extern "C" void kernel_launch(void* const* d_in, const int* in_sizes, int n_in,
                              void* d_out, int out_size, void* d_ws, size_t ws_size,
                              hipStream_t stream) {
    const float* x   = (const float*)d_in[0];
    const float* ctx = (const float*)d_in[1];
    const float* Wq  = (const float*)d_in[2];
    const float* Wk  = (const float*)d_in[3];
    const float* Wv  = (const float*)d_in[4];
    const int* lengths = (const int*)d_in[5];
    float* out = (float*)d_out;

    char* ws = (char*)d_ws;
    __bf16* Wt = (__bf16*)ws;                          // 768 KB
    __bf16* Qb = (__bf16*)(ws + 786432);               // 4 MB
    __bf16* Kb = (__bf16*)(ws + 786432 + 4194304);     // 4 MB
    __bf16* Vt = (__bf16*)(ws + 786432 + 8388608);     // 4 MB (V^T)
    float*  Vm = (float*) (ws + 786432 + 12582912);    // 4 KB

    convw_kernel<<<dim3(64, 3), 256, 0, stream>>>(Wq, Wk, Wv, Wt);
    proj_kernel<<<512, 256, 0, stream>>>(x, ctx, Wt, lengths, Qb, Kb, Vt);
    vmean_kernel<<<64, 256, 0, stream>>>(Vt, lengths, Vm);
    attn_kernel<<<512, 256, 0, stream>>>(Qb, Kb, Vt, lengths, Vm, out);
}

// Round 6
// 211.490 us; speedup vs baseline: 1.1211x; 1.0188x over previous
//
#include <hip/hip_runtime.h>
#include <hip/hip_bf16.h>

// Problem dims (fixed by setup_inputs)
#define BB 8
#define SS 2048
#define DD 1024
#define DKK 128

using bf16x8  = __attribute__((ext_vector_type(8))) __bf16;
using floatx4 = __attribute__((ext_vector_type(4))) float;
using intx4   = __attribute__((ext_vector_type(4))) int;

// async global->LDS, 16B/lane. LDS dest = wave-uniform base + lane*16 (HW rule).
__device__ __forceinline__ void lds16(const void* g, void* l) {
    __builtin_amdgcn_global_load_lds((const __attribute__((address_space(1))) void*)g,
                                     (__attribute__((address_space(3))) void*)l, 16, 0, 0);
}

__device__ __forceinline__ int pack2(float a, float b) {
    union { __bf16 h; unsigned short u; } ua, ub;
    ua.h = (__bf16)a; ub.h = (__bf16)b;
    return (int)(ua.u | ((unsigned)ub.u << 16));
}

// ---------------------------------------------------------------------------
// Kernel 0: W (fp32 [128][1024]) -> bf16, k-tile-major + 16B-block XOR swizzle
// ---------------------------------------------------------------------------
__global__ __launch_bounds__(256) void convw_kernel(
    const float* __restrict__ Wq, const float* __restrict__ Wk,
    const float* __restrict__ Wv, __bf16* __restrict__ Wt)
{
    const int z = blockIdx.y;
    const float* W = (z == 0) ? Wq : (z == 1) ? Wk : Wv;
    const int t  = blockIdx.x * 256 + threadIdx.x;   // 0..16383
    const int n  = t >> 7;
    const int k0 = (t & 127) * 8;
    float4 f0 = *(const float4*)(W + n * DD + k0);
    float4 f1 = *(const float4*)(W + n * DD + k0 + 4);
    bf16x8 v;
    v[0]=(__bf16)f0.x; v[1]=(__bf16)f0.y; v[2]=(__bf16)f0.z; v[3]=(__bf16)f0.w;
    v[4]=(__bf16)f1.x; v[5]=(__bf16)f1.y; v[6]=(__bf16)f1.z; v[7]=(__bf16)f1.w;
    const int kb  = (k0 >> 3) & 7;
    const int kbs = kb ^ (n & 7);
    *(bf16x8*)(Wt + (size_t)z * 131072 + ((k0 >> 6) * 128 + n) * 64 + kbs * 8) = v;
}

// ---------------------------------------------------------------------------
// Kernel 1: projections.  R5 change (T14 async-STAGE split): W staged via
// REGISTERS (global->reg issued one iteration ahead, ds_write at top of the
// consuming iteration) instead of global_load_lds.  __syncthreads' mandatory
// vmcnt(0) drain only waits LDS-bound traffic; register-dest loads stay in
// flight across the barrier, so W-load latency is hidden under a full
// compute phase (the R4 version paid it exposed 16x per block = ~3400cy/it).
// LDS image is a byte-identical linear copy -> compute reads unchanged.
// ---------------------------------------------------------------------------
__global__ __launch_bounds__(256) void proj_kernel(
    const float* __restrict__ x, const float* __restrict__ ctx,
    const __bf16* __restrict__ Wt, const int* __restrict__ lengths,
    __bf16* __restrict__ Qb, __bf16* __restrict__ Kb, __bf16* __restrict__ Vt)
{
    __shared__ __align__(16) __bf16 SH[20992];      // 41984 B
    __bf16* Abuf = SH;                              // 64 x 72 (padded)
    __bf16* Wl0  = SH + 4608;                       // 128 x 64 (swizzled image)
    __bf16* Wl1  = SH + 12800;
    __bf16* T    = SH + 4608;                       // V epilogue overlay, 128 x 72

    const int isV = blockIdx.x >= 256;
    const int m0  = (isV ? blockIdx.x - 256 : blockIdx.x) * 64;
    const int b   = m0 >> 11;
    const int s0  = m0 & (SS - 1);
    const int len = lengths[b];
    if (s0 >= len) return;                          // fully-padded tile

    const int tid  = threadIdx.x;
    const int wave = tid >> 6;
    const int lane = tid & 63;
    const int quad = lane >> 4;
    const int l16  = lane & 15;
    const int wm   = wave >> 1;
    const int wn   = wave & 1;

    const float*  A  = isV ? x : ctx;
    const __bf16* W0 = isV ? (Wt + 262144) : Wt;
    const __bf16* W1 = Wt + 131072;

    const int r    = tid >> 2;
    const int kseg = (tid & 3) * 16;
    const float* Ab = A + (size_t)(m0 + r) * DD + kseg;
    const int  wofs = tid * 32;                     // this thread's 32-elem span

    floatx4 acc[2][2][4];
#pragma unroll
    for (int m_ = 0; m_ < 2; ++m_)
#pragma unroll
        for (int i = 0; i < 2; ++i)
#pragma unroll
            for (int j = 0; j < 4; ++j) acc[m_][i][j] = (floatx4){0.f,0.f,0.f,0.f};

    // register-staged A (fp32) and W (bf16 image) for the CURRENT iteration
    float4 pf[4];
    bf16x8 wr0[4], wr1[4];
#pragma unroll
    for (int i = 0; i < 4; ++i) pf[i] = *(const float4*)(Ab + i * 4);
#pragma unroll
    for (int i = 0; i < 4; ++i)
        wr0[i] = *(const bf16x8*)(W0 + wofs + i * 8);
    if (!isV)
#pragma unroll
        for (int i = 0; i < 4; ++i)
            wr1[i] = *(const bf16x8*)(W1 + wofs + i * 8);

    for (int t = 0; t < 16; ++t) {
        __syncthreads();                      // compute(t-1) done: LDS writable
        // ---- write staged registers (iteration t data) into LDS ----
        {
            bf16x8 c0, c1;
            c0[0]=(__bf16)pf[0].x; c0[1]=(__bf16)pf[0].y; c0[2]=(__bf16)pf[0].z; c0[3]=(__bf16)pf[0].w;
            c0[4]=(__bf16)pf[1].x; c0[5]=(__bf16)pf[1].y; c0[6]=(__bf16)pf[1].z; c0[7]=(__bf16)pf[1].w;
            c1[0]=(__bf16)pf[2].x; c1[1]=(__bf16)pf[2].y; c1[2]=(__bf16)pf[2].z; c1[3]=(__bf16)pf[2].w;
            c1[4]=(__bf16)pf[3].x; c1[5]=(__bf16)pf[3].y; c1[6]=(__bf16)pf[3].z; c1[7]=(__bf16)pf[3].w;
            *(bf16x8*)&Abuf[r * 72 + kseg]     = c0;
            *(bf16x8*)&Abuf[r * 72 + kseg + 8] = c1;
        }
#pragma unroll
        for (int i = 0; i < 4; ++i) *(bf16x8*)&Wl0[wofs + i * 8] = wr0[i];
        if (!isV)
#pragma unroll
            for (int i = 0; i < 4; ++i) *(bf16x8*)&Wl1[wofs + i * 8] = wr1[i];

        // ---- issue next-iteration loads (registers: stay in flight across
        //      the barrier; consumed by next iter's ds_writes) ----
        if (t < 15) {
            const float* ap = Ab + (t + 1) * 64;
#pragma unroll
            for (int i = 0; i < 4; ++i) pf[i] = *(const float4*)(ap + i * 4);
            const __bf16* wp0 = W0 + (size_t)(t + 1) * 8192 + wofs;
#pragma unroll
            for (int i = 0; i < 4; ++i) wr0[i] = *(const bf16x8*)(wp0 + i * 8);
            if (!isV) {
                const __bf16* wp1 = W1 + (size_t)(t + 1) * 8192 + wofs;
#pragma unroll
                for (int i = 0; i < 4; ++i) wr1[i] = *(const bf16x8*)(wp1 + i * 8);
            }
        }
        __syncthreads();                      // LDS writes visible

#pragma unroll
        for (int kh = 0; kh < 2; ++kh) {
            bf16x8 af[2];
#pragma unroll
            for (int mt = 0; mt < 2; ++mt)
                af[mt] = *(const bf16x8*)&Abuf[(wm*32 + mt*16 + l16) * 72 + kh*32 + quad*8];
            const int kb = kh * 4 + quad;
#pragma unroll
            for (int nt = 0; nt < 4; ++nt) {
                const int n = wn * 64 + nt * 16 + l16;
                const int off = n * 64 + ((kb ^ (n & 7)) << 3);
                bf16x8 w0 = *(const bf16x8*)&Wl0[off];
#pragma unroll
                for (int mt = 0; mt < 2; ++mt)
                    acc[0][mt][nt] = __builtin_amdgcn_mfma_f32_16x16x32_bf16(af[mt], w0, acc[0][mt][nt], 0, 0, 0);
                if (!isV) {
                    bf16x8 w1 = *(const bf16x8*)&Wl1[off];
#pragma unroll
                    for (int mt = 0; mt < 2; ++mt)
                        acc[1][mt][nt] = __builtin_amdgcn_mfma_f32_16x16x32_bf16(af[mt], w1, acc[1][mt][nt], 0, 0, 0);
                }
            }
        }
    }

    if (!isV) {
#pragma unroll
        for (int mt = 0; mt < 2; ++mt)
#pragma unroll
            for (int rr = 0; rr < 4; ++rr) {
                const int row = m0 + wm*32 + mt*16 + quad*4 + rr;
                const float mk = ((row & (SS - 1)) < len) ? 1.f : 0.f;
#pragma unroll
                for (int nt = 0; nt < 4; ++nt) {
                    const int col = wn*64 + nt*16 + l16;
                    Qb[(size_t)row * DKK + col] = (__bf16)(acc[0][mt][nt][rr] * mk);
                    Kb[(size_t)row * DKK + col] = (__bf16)(acc[1][mt][nt][rr] * mk);
                }
            }
    } else {
        __syncthreads();
#pragma unroll
        for (int mt = 0; mt < 2; ++mt)
#pragma unroll
            for (int nt = 0; nt < 4; ++nt)
#pragma unroll
                for (int rr = 0; rr < 4; ++rr) {
                    const int s = wm*32 + mt*16 + quad*4 + rr;
                    const int n = wn*64 + nt*16 + l16;
                    const float mk = (s0 + s < len) ? 1.f : 0.f;
                    T[n * 72 + s] = (__bf16)(acc[0][mt][nt][rr] * mk);
                }
        __syncthreads();
        const int n = tid >> 1, h = tid & 1;
        __bf16* dst = Vt + (size_t)b * DKK * SS + (size_t)n * SS + s0 + h * 32;
#pragma unroll
        for (int i = 0; i < 4; ++i)
            *(bf16x8*)(dst + i * 8) = *(const bf16x8*)&T[n * 72 + h * 32 + i * 8];
    }
}

// ---------------------------------------------------------------------------
// Kernel 2: per-batch column mean of V (exact output for padded q-rows).
// ---------------------------------------------------------------------------
__global__ __launch_bounds__(256) void vmean_kernel(
    const __bf16* __restrict__ Vt, const int* __restrict__ lengths,
    float* __restrict__ Vmean)
{
    const int b   = blockIdx.x >> 3;
    const int g3  = blockIdx.x & 7;
    const int len = lengths[b];
    const int tid = threadIdx.x;
    const int n   = g3 * 16 + (tid >> 4);
    const int sl  = (tid & 15) * 128;                 // this thread's 128-elem span
    const __bf16* src = Vt + (size_t)b * DKK * SS + (size_t)n * SS + sl;
    float s = 0.f;
#pragma unroll
    for (int i = 0; i < 16; ++i) {
        bf16x8 v = *(const bf16x8*)(src + i * 8);
#pragma unroll
        for (int j = 0; j < 8; ++j)
            s += (sl + i * 8 + j < len) ? (float)v[j] : 0.f;
    }
#pragma unroll
    for (int off = 1; off < 16; off <<= 1)
        s += __shfl_xor(s, off, 64);
    if ((tid & 15) == 0) Vmean[b * DKK + n] = s / (float)len;
}

// ---------------------------------------------------------------------------
// Kernel 3: flash attention (unchanged from R4 — isolate proj this round).
// Block = 32 q-rows, grid 512; wave = (sub-tile, key-half); 64-key chunk
// staged in LDS (dbuf 64 KB); 2-way LDS reduce; fixed-max softmax.
// ---------------------------------------------------------------------------
__global__ __launch_bounds__(256) void attn_kernel(
    const __bf16* __restrict__ Qb, const __bf16* __restrict__ Kb,
    const __bf16* __restrict__ Vt, const int* __restrict__ lengths,
    const float* __restrict__ Vmean, float* __restrict__ out)
{
    __shared__ __align__(16) __bf16 KB[2 * 8192];   // 2 x [64 keys][128] 32 KB
    __shared__ __align__(16) __bf16 VB[2 * 8192];   // 2 x [128 dk][64 keys] 32 KB

    const int b    = blockIdx.x & 7;          // batch -> XCD pin (round-robin)
    const int qt   = 63 - (blockIdx.x >> 3);  // longest tiles dispatched first
    const int qw   = qt * 32;
    const int len  = lengths[b];
    const int tid  = threadIdx.x;
    const int wave = tid >> 6;
    const int lane = tid & 63;
    const int quad = lane >> 4;
    const int l16  = lane & 15;
    const int sub  = wave >> 1;               // q-subtile (16 rows)
    const int half = wave & 1;                // key half (32 keys)

    if (qw >= len) {                          // fully-padded tile: exact Vmean
        const int c8 = (tid & 15) * 8;
        const float4 v0 = *(const float4*)(Vmean + b * DKK + c8);
        const float4 v1 = *(const float4*)(Vmean + b * DKK + c8 + 4);
#pragma unroll
        for (int pass = 0; pass < 2; ++pass) {
            const int row = pass * 16 + (tid >> 4);
            float* op = out + (size_t)(b * SS + qw + row) * DKK + c8;
            *(float4*)op = v0; *(float4*)(op + 4) = v1;
        }
        return;                               // whole block returns: no barrier
    }

    const int jmax = min(qw + 32, len);       // causal: keys in [0, jmax)
    const int nc   = (jmax + 63) >> 6;        // 64-key chunks
    const __bf16* Kbase = Kb + (size_t)b * SS * DKK;
    const __bf16* Vbase = Vt + (size_t)b * DKK * SS;

    // Q fragments for this wave's 16 rows
    bf16x8 qfrag[4];
    {
        const __bf16* Qbase = Qb + (size_t)(b * SS + qw + sub * 16) * DKK;
#pragma unroll
        for (int cc = 0; cc < 4; ++cc)
            qfrag[cc] = *(const bf16x8*)(Qbase + (size_t)l16 * DKK + cc * 32 + quad * 8);
    }

    floatx4 oacc[8];
#pragma unroll
    for (int nt = 0; nt < 8; ++nt) oacc[nt] = (floatx4){0.f,0.f,0.f,0.f};
    float lsum = 0.f;                         // per-lane, q = l16 (this half)
    const float scale = 0.08838834764831845f; // 1/sqrt(128)
    const int   iq    = qw + sub * 16 + l16;
    const int   sw7   = l16 & 7;              // read-side swizzle key

    auto stageK = [&](int buf, int j0) {
#pragma unroll
        for (int i = 0; i < 4; ++i) {
            const int c   = wave * 4 + i;           // 0..15
            const int row = c * 4 + quad;           // 0..63
            const int sb  = l16 ^ (row & 7);        // inverse-swizzled src blk
            lds16(Kbase + (size_t)(j0 + row) * DKK + sb * 8,
                  KB + buf * 8192 + c * 512);
        }
    };
    auto stageV = [&](int buf, int j0) {
#pragma unroll
        for (int i = 0; i < 4; ++i) {
            const int c   = wave * 4 + i;           // 0..15
            const int row = c * 8 + (lane >> 3);    // 0..127
            const int sb  = (lane & 7) ^ (row & 7);
            lds16(Vbase + (size_t)row * SS + j0 + sb * 8,
                  VB + buf * 8192 + c * 512);
        }
    };

    auto process = [&](int buf, int j0) {
        const int kbas = buf * 8192;
        floatx4 st[2];
#pragma unroll
        for (int jt = 0; jt < 2; ++jt) {
            st[jt] = (floatx4){0.f,0.f,0.f,0.f};
#pragma unroll
            for (int cc = 0; cc < 4; ++cc) {
                bf16x8 kf = *(const bf16x8*)(
                    KB + kbas + ((half*2 + jt)*16 + l16) * 128 + (((cc*4 + quad) ^ sw7) * 8));
                st[jt] = __builtin_amdgcn_mfma_f32_16x16x32_bf16(
                    kf, qfrag[cc], st[jt], 0, 0, 0);
            }
        }
        int pk[2][2];
#pragma unroll
        for (int jt = 0; jt < 2; ++jt) {
            float p[4];
#pragma unroll
            for (int rr = 0; rr < 4; ++rr) {
                const int j = j0 + half*32 + jt*16 + quad*4 + rr;
                p[rr] = (j > iq || j >= len) ? 0.f : __expf(st[jt][rr] * scale - 8.f);
                lsum += p[rr];
            }
            pk[jt][0] = pack2(p[0], p[1]);
            pk[jt][1] = pack2(p[2], p[3]);
        }
        const int a0 = (((quad & 1) << 5) + l16) << 2;
        const int a1 = a0 + 64;
        const int r00 = __builtin_amdgcn_ds_bpermute(a0, pk[0][0]);
        const int r01 = __builtin_amdgcn_ds_bpermute(a0, pk[0][1]);
        const int r02 = __builtin_amdgcn_ds_bpermute(a0, pk[1][0]);
        const int r03 = __builtin_amdgcn_ds_bpermute(a0, pk[1][1]);
        const int r10 = __builtin_amdgcn_ds_bpermute(a1, pk[0][0]);
        const int r11 = __builtin_amdgcn_ds_bpermute(a1, pk[0][1]);
        const int r12 = __builtin_amdgcn_ds_bpermute(a1, pk[1][0]);
        const int r13 = __builtin_amdgcn_ds_bpermute(a1, pk[1][1]);
        const bool hi = quad >= 2;
        union { intx4 i; bf16x8 h; } u;
        u.i = (intx4){ hi ? r02 : r00, hi ? r03 : r01,
                       hi ? r12 : r10, hi ? r13 : r11 };
#pragma unroll
        for (int nt = 0; nt < 8; ++nt) {
            bf16x8 vf = *(const bf16x8*)(
                VB + kbas + (nt*16 + l16) * 64 + (((half*4 + quad) ^ sw7) * 8));
            oacc[nt] = __builtin_amdgcn_mfma_f32_16x16x32_bf16(
                u.h, vf, oacc[nt], 0, 0, 0);
        }
    };

    stageK(0, 0); stageV(0, 0);
    __syncthreads();
    for (int c = 0; c < nc; ++c) {
        const int cur = c & 1;
        if (c + 1 < nc) { stageK(cur ^ 1, (c + 1) * 64); stageV(cur ^ 1, (c + 1) * 64); }
        process(cur, c * 64);
        __syncthreads();
    }

    lsum += __shfl_xor(lsum, 16, 64);
    lsum += __shfl_xor(lsum, 32, 64);

    float* Ored = (float*)KB;                 // 2 x [16][128] f32 = 16 KB
    float* Lred = (float*)VB;                 // 2 x [16] f32
    if (half) {
#pragma unroll
        for (int nt = 0; nt < 8; ++nt)
#pragma unroll
            for (int rr = 0; rr < 4; ++rr)
                Ored[sub*2048 + (quad*4 + rr)*128 + nt*16 + l16] = oacc[nt][rr];
        if (lane < 16) Lred[sub*16 + l16] = lsum;
    }
    __syncthreads();
    if (!half) {
        const float lt = lsum + Lred[sub*16 + l16];   // row-total for q = l16
        float inv[4];
#pragma unroll
        for (int rr = 0; rr < 4; ++rr)
            inv[rr] = 1.f / __shfl(lt, quad * 4 + rr, 64);
#pragma unroll
        for (int nt = 0; nt < 8; ++nt)
#pragma unroll
            for (int rr = 0; rr < 4; ++rr)
                out[(size_t)(b * SS + qw + sub*16 + quad*4 + rr) * DKK + nt*16 + l16] =
                    (oacc[nt][rr] + Ored[sub*2048 + (quad*4 + rr)*128 + nt*16 + l16]) * inv[rr];
    }
}

extern "C" void kernel_launch(void* const* d_in, const int* in_sizes, int n_in,
                              void* d_out, int out_size, void* d_ws, size_t ws_size,
                              hipStream_t stream) {
    const float* x   = (const float*)d_in[0];
    const float* ctx = (const float*)d_in[1];
    const float* Wq  = (const float*)d_in[2];
    const float* Wk  = (const float*)d_in[3];
    const float* Wv  = (const float*)d_in[4];
    const int* lengths = (const int*)d_in[5];
    float* out = (float*)d_out;

    char* ws = (char*)d_ws;
    __bf16* Wt = (__bf16*)ws;                          // 768 KB
    __bf16* Qb = (__bf16*)(ws + 786432);               // 4 MB
    __bf16* Kb = (__bf16*)(ws + 786432 + 4194304);     // 4 MB
    __bf16* Vt = (__bf16*)(ws + 786432 + 8388608);     // 4 MB (V^T)
    float*  Vm = (float*) (ws + 786432 + 12582912);    // 4 KB

    convw_kernel<<<dim3(64, 3), 256, 0, stream>>>(Wq, Wk, Wv, Wt);
    proj_kernel<<<512, 256, 0, stream>>>(x, ctx, Wt, lengths, Qb, Kb, Vt);
    vmean_kernel<<<64, 256, 0, stream>>>(Vt, lengths, Vm);
    attn_kernel<<<512, 256, 0, stream>>>(Qb, Kb, Vt, lengths, Vm, out);
}

// Round 7
// 208.941 us; speedup vs baseline: 1.1347x; 1.0122x over previous
//
#include <hip/hip_runtime.h>
#include <hip/hip_bf16.h>

// Problem dims (fixed by setup_inputs)
#define BB 8
#define SS 2048
#define DD 1024
#define DKK 128

using bf16x8  = __attribute__((ext_vector_type(8))) __bf16;
using floatx4 = __attribute__((ext_vector_type(4))) float;
using intx4   = __attribute__((ext_vector_type(4))) int;

// async global->LDS, 16B/lane. LDS dest = wave-uniform base + lane*16 (HW rule).
__device__ __forceinline__ void lds16(const void* g, void* l) {
    __builtin_amdgcn_global_load_lds((const __attribute__((address_space(1))) void*)g,
                                     (__attribute__((address_space(3))) void*)l, 16, 0, 0);
}

__device__ __forceinline__ int pack2(float a, float b) {
    union { __bf16 h; unsigned short u; } ua, ub;
    ua.h = (__bf16)a; ub.h = (__bf16)b;
    return (int)(ua.u | ((unsigned)ub.u << 16));
}

// ---------------------------------------------------------------------------
// Kernel 0: W (fp32 [128][1024]) -> bf16, k-tile-major + 16B-block XOR swizzle
// ---------------------------------------------------------------------------
__global__ __launch_bounds__(256) void convw_kernel(
    const float* __restrict__ Wq, const float* __restrict__ Wk,
    const float* __restrict__ Wv, __bf16* __restrict__ Wt)
{
    const int z = blockIdx.y;
    const float* W = (z == 0) ? Wq : (z == 1) ? Wk : Wv;
    const int t  = blockIdx.x * 256 + threadIdx.x;   // 0..16383
    const int n  = t >> 7;
    const int k0 = (t & 127) * 8;
    float4 f0 = *(const float4*)(W + n * DD + k0);
    float4 f1 = *(const float4*)(W + n * DD + k0 + 4);
    bf16x8 v;
    v[0]=(__bf16)f0.x; v[1]=(__bf16)f0.y; v[2]=(__bf16)f0.z; v[3]=(__bf16)f0.w;
    v[4]=(__bf16)f1.x; v[5]=(__bf16)f1.y; v[6]=(__bf16)f1.z; v[7]=(__bf16)f1.w;
    const int kb  = (k0 >> 3) & 7;
    const int kbs = kb ^ (n & 7);
    *(bf16x8*)(Wt + (size_t)z * 131072 + ((k0 >> 6) * 128 + n) * 64 + kbs * 8) = v;
}

// ---------------------------------------------------------------------------
// Kernel 1: projections.  R6 change: fix the 32-way bank conflict introduced
// by R5's W register-staging ds_write.  Thread now carries 4 SCATTERED 16B
// blocks (element i*2048 + tid*8) instead of a contiguous 64B span: lane
// stride is 16B (canonical conflict-free), global load is a contiguous
// 1KB/wave/instruction, and the LDS image is still the identity mapping so
// compute reads are byte-identical.  (R5 counters: bank conflicts 414K ->
// 3.82M -- that ds_write serialization ate the T14 latency win.)
// ---------------------------------------------------------------------------
__global__ __launch_bounds__(256) void proj_kernel(
    const float* __restrict__ x, const float* __restrict__ ctx,
    const __bf16* __restrict__ Wt, const int* __restrict__ lengths,
    __bf16* __restrict__ Qb, __bf16* __restrict__ Kb, __bf16* __restrict__ Vt)
{
    __shared__ __align__(16) __bf16 SH[20992];      // 41984 B
    __bf16* Abuf = SH;                              // 64 x 72 (padded)
    __bf16* Wl0  = SH + 4608;                       // 128 x 64 (swizzled image)
    __bf16* Wl1  = SH + 12800;
    __bf16* T    = SH + 4608;                       // V epilogue overlay, 128 x 72

    const int isV = blockIdx.x >= 256;
    const int m0  = (isV ? blockIdx.x - 256 : blockIdx.x) * 64;
    const int b   = m0 >> 11;
    const int s0  = m0 & (SS - 1);
    const int len = lengths[b];
    if (s0 >= len) return;                          // fully-padded tile

    const int tid  = threadIdx.x;
    const int wave = tid >> 6;
    const int lane = tid & 63;
    const int quad = lane >> 4;
    const int l16  = lane & 15;
    const int wm   = wave >> 1;
    const int wn   = wave & 1;

    const float*  A  = isV ? x : ctx;
    const __bf16* W0 = isV ? (Wt + 262144) : Wt;
    const __bf16* W1 = Wt + 131072;

    const int r    = tid >> 2;
    const int kseg = (tid & 3) * 16;
    const float* Ab = A + (size_t)(m0 + r) * DD + kseg;
    const int  wel  = tid * 8;                      // 16B block element offset

    floatx4 acc[2][2][4];
#pragma unroll
    for (int m_ = 0; m_ < 2; ++m_)
#pragma unroll
        for (int i = 0; i < 2; ++i)
#pragma unroll
            for (int j = 0; j < 4; ++j) acc[m_][i][j] = (floatx4){0.f,0.f,0.f,0.f};

    // register-staged A (fp32) and W (bf16 image) for the CURRENT iteration
    float4 pf[4];
    bf16x8 wr0[4], wr1[4];
#pragma unroll
    for (int i = 0; i < 4; ++i) pf[i] = *(const float4*)(Ab + i * 4);
#pragma unroll
    for (int i = 0; i < 4; ++i)
        wr0[i] = *(const bf16x8*)(W0 + i * 2048 + wel);
    if (!isV)
#pragma unroll
        for (int i = 0; i < 4; ++i)
            wr1[i] = *(const bf16x8*)(W1 + i * 2048 + wel);

    for (int t = 0; t < 16; ++t) {
        __syncthreads();                      // compute(t-1) done: LDS writable
        // ---- write staged registers (iteration t data) into LDS ----
        {
            bf16x8 c0, c1;
            c0[0]=(__bf16)pf[0].x; c0[1]=(__bf16)pf[0].y; c0[2]=(__bf16)pf[0].z; c0[3]=(__bf16)pf[0].w;
            c0[4]=(__bf16)pf[1].x; c0[5]=(__bf16)pf[1].y; c0[6]=(__bf16)pf[1].z; c0[7]=(__bf16)pf[1].w;
            c1[0]=(__bf16)pf[2].x; c1[1]=(__bf16)pf[2].y; c1[2]=(__bf16)pf[2].z; c1[3]=(__bf16)pf[2].w;
            c1[4]=(__bf16)pf[3].x; c1[5]=(__bf16)pf[3].y; c1[6]=(__bf16)pf[3].z; c1[7]=(__bf16)pf[3].w;
            *(bf16x8*)&Abuf[r * 72 + kseg]     = c0;
            *(bf16x8*)&Abuf[r * 72 + kseg + 8] = c1;
        }
#pragma unroll
        for (int i = 0; i < 4; ++i) *(bf16x8*)&Wl0[i * 2048 + wel] = wr0[i];
        if (!isV)
#pragma unroll
            for (int i = 0; i < 4; ++i) *(bf16x8*)&Wl1[i * 2048 + wel] = wr1[i];

        // ---- issue next-iteration loads (registers: stay in flight across
        //      the barrier; consumed by next iter's ds_writes) ----
        if (t < 15) {
            const float* ap = Ab + (t + 1) * 64;
#pragma unroll
            for (int i = 0; i < 4; ++i) pf[i] = *(const float4*)(ap + i * 4);
            const __bf16* wp0 = W0 + (size_t)(t + 1) * 8192 + wel;
#pragma unroll
            for (int i = 0; i < 4; ++i) wr0[i] = *(const bf16x8*)(wp0 + i * 2048);
            if (!isV) {
                const __bf16* wp1 = W1 + (size_t)(t + 1) * 8192 + wel;
#pragma unroll
                for (int i = 0; i < 4; ++i) wr1[i] = *(const bf16x8*)(wp1 + i * 2048);
            }
        }
        __syncthreads();                      // LDS writes visible

#pragma unroll
        for (int kh = 0; kh < 2; ++kh) {
            bf16x8 af[2];
#pragma unroll
            for (int mt = 0; mt < 2; ++mt)
                af[mt] = *(const bf16x8*)&Abuf[(wm*32 + mt*16 + l16) * 72 + kh*32 + quad*8];
            const int kb = kh * 4 + quad;
#pragma unroll
            for (int nt = 0; nt < 4; ++nt) {
                const int n = wn * 64 + nt * 16 + l16;
                const int off = n * 64 + ((kb ^ (n & 7)) << 3);
                bf16x8 w0 = *(const bf16x8*)&Wl0[off];
#pragma unroll
                for (int mt = 0; mt < 2; ++mt)
                    acc[0][mt][nt] = __builtin_amdgcn_mfma_f32_16x16x32_bf16(af[mt], w0, acc[0][mt][nt], 0, 0, 0);
                if (!isV) {
                    bf16x8 w1 = *(const bf16x8*)&Wl1[off];
#pragma unroll
                    for (int mt = 0; mt < 2; ++mt)
                        acc[1][mt][nt] = __builtin_amdgcn_mfma_f32_16x16x32_bf16(af[mt], w1, acc[1][mt][nt], 0, 0, 0);
                }
            }
        }
    }

    if (!isV) {
#pragma unroll
        for (int mt = 0; mt < 2; ++mt)
#pragma unroll
            for (int rr = 0; rr < 4; ++rr) {
                const int row = m0 + wm*32 + mt*16 + quad*4 + rr;
                const float mk = ((row & (SS - 1)) < len) ? 1.f : 0.f;
#pragma unroll
                for (int nt = 0; nt < 4; ++nt) {
                    const int col = wn*64 + nt*16 + l16;
                    Qb[(size_t)row * DKK + col] = (__bf16)(acc[0][mt][nt][rr] * mk);
                    Kb[(size_t)row * DKK + col] = (__bf16)(acc[1][mt][nt][rr] * mk);
                }
            }
    } else {
        __syncthreads();
#pragma unroll
        for (int mt = 0; mt < 2; ++mt)
#pragma unroll
            for (int nt = 0; nt < 4; ++nt)
#pragma unroll
                for (int rr = 0; rr < 4; ++rr) {
                    const int s = wm*32 + mt*16 + quad*4 + rr;
                    const int n = wn*64 + nt*16 + l16;
                    const float mk = (s0 + s < len) ? 1.f : 0.f;
                    T[n * 72 + s] = (__bf16)(acc[0][mt][nt][rr] * mk);
                }
        __syncthreads();
        const int n = tid >> 1, h = tid & 1;
        __bf16* dst = Vt + (size_t)b * DKK * SS + (size_t)n * SS + s0 + h * 32;
#pragma unroll
        for (int i = 0; i < 4; ++i)
            *(bf16x8*)(dst + i * 8) = *(const bf16x8*)&T[n * 72 + h * 32 + i * 8];
    }
}

// ---------------------------------------------------------------------------
// Kernel 2: per-batch column mean of V (exact output for padded q-rows).
// ---------------------------------------------------------------------------
__global__ __launch_bounds__(256) void vmean_kernel(
    const __bf16* __restrict__ Vt, const int* __restrict__ lengths,
    float* __restrict__ Vmean)
{
    const int b   = blockIdx.x >> 3;
    const int g3  = blockIdx.x & 7;
    const int len = lengths[b];
    const int tid = threadIdx.x;
    const int n   = g3 * 16 + (tid >> 4);
    const int sl  = (tid & 15) * 128;                 // this thread's 128-elem span
    const __bf16* src = Vt + (size_t)b * DKK * SS + (size_t)n * SS + sl;
    float s = 0.f;
#pragma unroll
    for (int i = 0; i < 16; ++i) {
        bf16x8 v = *(const bf16x8*)(src + i * 8);
#pragma unroll
        for (int j = 0; j < 8; ++j)
            s += (sl + i * 8 + j < len) ? (float)v[j] : 0.f;
    }
#pragma unroll
    for (int off = 1; off < 16; off <<= 1)
        s += __shfl_xor(s, off, 64);
    if ((tid & 15) == 0) Vmean[b * DKK + n] = s / (float)len;
}

// ---------------------------------------------------------------------------
// Kernel 3: flash attention (structure = R4, verified).  R6 change: qt remap
// for uniform per-CU load.  XCD round-robin gives a CU blocks i and i+32
// (in units of blockIdx>>3); with qt(i) = i<32 ? 63-i : i-32 the pair's
// causal chunk total is (64-i)+(i-31) = 33 units on EVERY CU (was 48..18
// with the monotone longest-first map -> makespan tracked the 48s).
// ---------------------------------------------------------------------------
__global__ __launch_bounds__(256) void attn_kernel(
    const __bf16* __restrict__ Qb, const __bf16* __restrict__ Kb,
    const __bf16* __restrict__ Vt, const int* __restrict__ lengths,
    const float* __restrict__ Vmean, float* __restrict__ out)
{
    __shared__ __align__(16) __bf16 KB[2 * 8192];   // 2 x [64 keys][128] 32 KB
    __shared__ __align__(16) __bf16 VB[2 * 8192];   // 2 x [128 dk][64 keys] 32 KB

    const int b    = blockIdx.x & 7;          // batch -> XCD pin (round-robin)
    const int ii   = blockIdx.x >> 3;         // 0..63
    const int qt   = (ii < 32) ? (63 - ii) : (ii - 32);   // pair-balanced map
    const int qw   = qt * 32;
    const int len  = lengths[b];
    const int tid  = threadIdx.x;
    const int wave = tid >> 6;
    const int lane = tid & 63;
    const int quad = lane >> 4;
    const int l16  = lane & 15;
    const int sub  = wave >> 1;               // q-subtile (16 rows)
    const int half = wave & 1;                // key half (32 keys)

    if (qw >= len) {                          // fully-padded tile: exact Vmean
        const int c8 = (tid & 15) * 8;
        const float4 v0 = *(const float4*)(Vmean + b * DKK + c8);
        const float4 v1 = *(const float4*)(Vmean + b * DKK + c8 + 4);
#pragma unroll
        for (int pass = 0; pass < 2; ++pass) {
            const int row = pass * 16 + (tid >> 4);
            float* op = out + (size_t)(b * SS + qw + row) * DKK + c8;
            *(float4*)op = v0; *(float4*)(op + 4) = v1;
        }
        return;                               // whole block returns: no barrier
    }

    const int jmax = min(qw + 32, len);       // causal: keys in [0, jmax)
    const int nc   = (jmax + 63) >> 6;        // 64-key chunks
    const __bf16* Kbase = Kb + (size_t)b * SS * DKK;
    const __bf16* Vbase = Vt + (size_t)b * DKK * SS;

    // Q fragments for this wave's 16 rows
    bf16x8 qfrag[4];
    {
        const __bf16* Qbase = Qb + (size_t)(b * SS + qw + sub * 16) * DKK;
#pragma unroll
        for (int cc = 0; cc < 4; ++cc)
            qfrag[cc] = *(const bf16x8*)(Qbase + (size_t)l16 * DKK + cc * 32 + quad * 8);
    }

    floatx4 oacc[8];
#pragma unroll
    for (int nt = 0; nt < 8; ++nt) oacc[nt] = (floatx4){0.f,0.f,0.f,0.f};
    float lsum = 0.f;                         // per-lane, q = l16 (this half)
    const float scale = 0.08838834764831845f; // 1/sqrt(128)
    const int   iq    = qw + sub * 16 + l16;
    const int   sw7   = l16 & 7;              // read-side swizzle key

    auto stageK = [&](int buf, int j0) {
#pragma unroll
        for (int i = 0; i < 4; ++i) {
            const int c   = wave * 4 + i;           // 0..15
            const int row = c * 4 + quad;           // 0..63
            const int sb  = l16 ^ (row & 7);        // inverse-swizzled src blk
            lds16(Kbase + (size_t)(j0 + row) * DKK + sb * 8,
                  KB + buf * 8192 + c * 512);
        }
    };
    auto stageV = [&](int buf, int j0) {
#pragma unroll
        for (int i = 0; i < 4; ++i) {
            const int c   = wave * 4 + i;           // 0..15
            const int row = c * 8 + (lane >> 3);    // 0..127
            const int sb  = (lane & 7) ^ (row & 7);
            lds16(Vbase + (size_t)row * SS + j0 + sb * 8,
                  VB + buf * 8192 + c * 512);
        }
    };

    auto process = [&](int buf, int j0) {
        const int kbas = buf * 8192;
        floatx4 st[2];
#pragma unroll
        for (int jt = 0; jt < 2; ++jt) {
            st[jt] = (floatx4){0.f,0.f,0.f,0.f};
#pragma unroll
            for (int cc = 0; cc < 4; ++cc) {
                bf16x8 kf = *(const bf16x8*)(
                    KB + kbas + ((half*2 + jt)*16 + l16) * 128 + (((cc*4 + quad) ^ sw7) * 8));
                st[jt] = __builtin_amdgcn_mfma_f32_16x16x32_bf16(
                    kf, qfrag[cc], st[jt], 0, 0, 0);
            }
        }
        int pk[2][2];
#pragma unroll
        for (int jt = 0; jt < 2; ++jt) {
            float p[4];
#pragma unroll
            for (int rr = 0; rr < 4; ++rr) {
                const int j = j0 + half*32 + jt*16 + quad*4 + rr;
                p[rr] = (j > iq || j >= len) ? 0.f : __expf(st[jt][rr] * scale - 8.f);
                lsum += p[rr];
            }
            pk[jt][0] = pack2(p[0], p[1]);
            pk[jt][1] = pack2(p[2], p[3]);
        }
        const int a0 = (((quad & 1) << 5) + l16) << 2;
        const int a1 = a0 + 64;
        const int r00 = __builtin_amdgcn_ds_bpermute(a0, pk[0][0]);
        const int r01 = __builtin_amdgcn_ds_bpermute(a0, pk[0][1]);
        const int r02 = __builtin_amdgcn_ds_bpermute(a0, pk[1][0]);
        const int r03 = __builtin_amdgcn_ds_bpermute(a0, pk[1][1]);
        const int r10 = __builtin_amdgcn_ds_bpermute(a1, pk[0][0]);
        const int r11 = __builtin_amdgcn_ds_bpermute(a1, pk[0][1]);
        const int r12 = __builtin_amdgcn_ds_bpermute(a1, pk[1][0]);
        const int r13 = __builtin_amdgcn_ds_bpermute(a1, pk[1][1]);
        const bool hi = quad >= 2;
        union { intx4 i; bf16x8 h; } u;
        u.i = (intx4){ hi ? r02 : r00, hi ? r03 : r01,
                       hi ? r12 : r10, hi ? r13 : r11 };
#pragma unroll
        for (int nt = 0; nt < 8; ++nt) {
            bf16x8 vf = *(const bf16x8*)(
                VB + kbas + (nt*16 + l16) * 64 + (((half*4 + quad) ^ sw7) * 8));
            oacc[nt] = __builtin_amdgcn_mfma_f32_16x16x32_bf16(
                u.h, vf, oacc[nt], 0, 0, 0);
        }
    };

    stageK(0, 0); stageV(0, 0);
    __syncthreads();
    for (int c = 0; c < nc; ++c) {
        const int cur = c & 1;
        if (c + 1 < nc) { stageK(cur ^ 1, (c + 1) * 64); stageV(cur ^ 1, (c + 1) * 64); }
        process(cur, c * 64);
        __syncthreads();
    }

    lsum += __shfl_xor(lsum, 16, 64);
    lsum += __shfl_xor(lsum, 32, 64);

    float* Ored = (float*)KB;                 // 2 x [16][128] f32 = 16 KB
    float* Lred = (float*)VB;                 // 2 x [16] f32
    if (half) {
#pragma unroll
        for (int nt = 0; nt < 8; ++nt)
#pragma unroll
            for (int rr = 0; rr < 4; ++rr)
                Ored[sub*2048 + (quad*4 + rr)*128 + nt*16 + l16] = oacc[nt][rr];
        if (lane < 16) Lred[sub*16 + l16] = lsum;
    }
    __syncthreads();
    if (!half) {
        const float lt = lsum + Lred[sub*16 + l16];   // row-total for q = l16
        float inv[4];
#pragma unroll
        for (int rr = 0; rr < 4; ++rr)
            inv[rr] = 1.f / __shfl(lt, quad * 4 + rr, 64);
#pragma unroll
        for (int nt = 0; nt < 8; ++nt)
#pragma unroll
            for (int rr = 0; rr < 4; ++rr)
                out[(size_t)(b * SS + qw + sub*16 + quad*4 + rr) * DKK + nt*16 + l16] =
                    (oacc[nt][rr] + Ored[sub*2048 + (quad*4 + rr)*128 + nt*16 + l16]) * inv[rr];
    }
}

extern "C" void kernel_launch(void* const* d_in, const int* in_sizes, int n_in,
                              void* d_out, int out_size, void* d_ws, size_t ws_size,
                              hipStream_t stream) {
    const float* x   = (const float*)d_in[0];
    const float* ctx = (const float*)d_in[1];
    const float* Wq  = (const float*)d_in[2];
    const float* Wk  = (const float*)d_in[3];
    const float* Wv  = (const float*)d_in[4];
    const int* lengths = (const int*)d_in[5];
    float* out = (float*)d_out;

    char* ws = (char*)d_ws;
    __bf16* Wt = (__bf16*)ws;                          // 768 KB
    __bf16* Qb = (__bf16*)(ws + 786432);               // 4 MB
    __bf16* Kb = (__bf16*)(ws + 786432 + 4194304);     // 4 MB
    __bf16* Vt = (__bf16*)(ws + 786432 + 8388608);     // 4 MB (V^T)
    float*  Vm = (float*) (ws + 786432 + 12582912);    // 4 KB

    convw_kernel<<<dim3(64, 3), 256, 0, stream>>>(Wq, Wk, Wv, Wt);
    proj_kernel<<<512, 256, 0, stream>>>(x, ctx, Wt, lengths, Qb, Kb, Vt);
    vmean_kernel<<<64, 256, 0, stream>>>(Vt, lengths, Vm);
    attn_kernel<<<512, 256, 0, stream>>>(Qb, Kb, Vt, lengths, Vm, out);
}